// Round 2
// baseline (2467.210 us; speedup 1.0000x reference)
//
#include <hip/hip_runtime.h>
#include <cstdint>
#include <cstddef>

// ---------------------------------------------------------------------------
// Qwen3.5 GatedDeltaNet forward, MI355X (gfx950), f16-MFMA implementation.
// B=2, S=4096, H=2048, HK=16, HV=32, DK=DV=128, KW=4, CS=64.
// Workspace peak: 370 MiB (hand-aliased layout, see kernel_launch).
// ---------------------------------------------------------------------------

typedef _Float16 half_t;
typedef _Float16 half2_t __attribute__((ext_vector_type(2)));
typedef _Float16 half4_t __attribute__((ext_vector_type(4)));
typedef _Float16 half8   __attribute__((ext_vector_type(8)));
typedef float    f32x4   __attribute__((ext_vector_type(4)));

#define MFMA16(a, b, c) __builtin_amdgcn_mfma_f32_16x16x32_f16((a), (b), (c), 0, 0, 0)

#define AS1 __attribute__((address_space(1)))
#define AS3 __attribute__((address_space(3)))

// async global->LDS, 16B per lane; LDS dest is wave-uniform base + lane*16.
__device__ __forceinline__ void gload16(void* lds, const void* g) {
    __builtin_amdgcn_global_load_lds((AS1 void*)(g), (AS3 void*)(lds), 16, 0, 0);
}

// ---- swizzled-LDS access helpers (XOR byte-bits 4..6 with row&7) ----------
// f32 array, rows of 64 floats (256 B). Used for A/T (in-place solve).
__device__ __forceinline__ float at_rd(const float* AT, int i, int j) {
    return *(const float*)((const char*)AT + i * 256 + ((j * 4) ^ ((i & 7) << 4)));
}
__device__ __forceinline__ void at_wr(float* AT, int i, int j, float v) {
    *(float*)((char*)AT + i * 256 + ((j * 4) ^ ((i & 7) << 4))) = v;
}
// f16 array, rows of 64 halfs (128 B): XT, vnT, kdT.
__device__ __forceinline__ half8 frag64(const half_t* base, int row, int koff) {
    return *(const half8*)((const char*)base + row * 128 + ((koff * 2) ^ ((row & 7) << 4)));
}
__device__ __forceinline__ void w64(half_t* base, int row, int col, float v) {
    *(half_t*)((char*)base + row * 128 + ((col * 2) ^ ((row & 7) << 4))) = (half_t)v;
}
// f16 array, rows of 128 halfs (256 B): SH (state^T).
__device__ __forceinline__ half8 frag128(const half_t* base, int row, int koff) {
    return *(const half8*)((const char*)base + row * 256 + ((koff * 2) ^ ((row & 7) << 4)));
}

// ---------------------------------------------------------------------------
// Cast / transpose prep kernels
// ---------------------------------------------------------------------------
__global__ __launch_bounds__(256) void cast_h_k(const float* __restrict__ src,
                                                half_t* __restrict__ dst) {
    long i = (long)blockIdx.x * 256 + threadIdx.x;  // processes 4 elems
    f32x4 v = *(const f32x4*)(src + i * 4);
    half4_t h;
    h[0] = (half_t)v[0]; h[1] = (half_t)v[1]; h[2] = (half_t)v[2]; h[3] = (half_t)v[3];
    *(half4_t*)(dst + i * 4) = h;
}

// Column-permuted W1T[n][k]:
//   n in [0,2048)     : q flat   (kh=n>>7, d=n&127)       -> Wq col kh*768+d
//   n in [2048,4096)  : k flat                             -> Wq col kh*768+128+d
//   n in [4096,8192)  : v flat   (vh=(n-4096)>>7)          -> Wq col kh*768+256+jj*128+d
//   n in [8192,8256)  : ba                                 -> Wba col n-8192
//   n in [8256,8320)  : zero pad
//   n in [8320,12416) : z flat   (vh=(n-8320)>>7)          -> Wq col kh*768+512+jj*128+d
__global__ __launch_bounds__(256) void build_w1t_k(const float* __restrict__ Wq,
                                                   const float* __restrict__ Wba,
                                                   half_t* __restrict__ W1T) {
    __shared__ half_t tile[32][33];
    int n0 = blockIdx.x * 32, k0 = blockIdx.y * 32;
    int tx = threadIdx.x & 31, ty = threadIdx.x >> 5;
#pragma unroll
    for (int t = 0; t < 4; ++t) {
        int k = k0 + ty + t * 8, n = n0 + tx;
        float v = 0.f;
        if (n < 2048) {
            int kh = n >> 7, d = n & 127;
            v = Wq[(long)k * 12288 + kh * 768 + d];
        } else if (n < 4096) {
            int n2 = n - 2048; int kh = n2 >> 7, d = n2 & 127;
            v = Wq[(long)k * 12288 + kh * 768 + 128 + d];
        } else if (n < 8192) {
            int n3 = n - 4096; int vh = n3 >> 7, d = n3 & 127;
            int kh = vh >> 1, jj = vh & 1;
            v = Wq[(long)k * 12288 + kh * 768 + 256 + jj * 128 + d];
        } else if (n < 8256) {
            v = Wba[(long)k * 64 + (n - 8192)];
        } else if (n >= 8320) {
            int n4 = n - 8320; int vh = n4 >> 7, d = n4 & 127;
            int kh = vh >> 1, jj = vh & 1;
            v = Wq[(long)k * 12288 + kh * 768 + 512 + jj * 128 + d];
        }
        tile[ty + t * 8][tx] = (half_t)v;
    }
    __syncthreads();
#pragma unroll
    for (int t = 0; t < 4; ++t) {
        int n = n0 + ty + t * 8, k = k0 + tx;
        W1T[(long)n * 2048 + k] = tile[tx][ty + t * 8];
    }
}

// WoT[n][k] = W_out[k][n]; n < 2048, k < 4096
__global__ __launch_bounds__(256) void build_wot_k(const float* __restrict__ Wo,
                                                   half_t* __restrict__ WoT) {
    __shared__ half_t tile[32][33];
    int n0 = blockIdx.x * 32, k0 = blockIdx.y * 32;
    int tx = threadIdx.x & 31, ty = threadIdx.x >> 5;
#pragma unroll
    for (int t = 0; t < 4; ++t) {
        int k = k0 + ty + t * 8, n = n0 + tx;
        tile[ty + t * 8][tx] = (half_t)Wo[(long)k * 2048 + n];
    }
    __syncthreads();
#pragma unroll
    for (int t = 0; t < 4; ++t) {
        int n = n0 + ty + t * 8, k = k0 + tx;
        WoT[(long)n * 4096 + k] = tile[tx][ty + t * 8];
    }
}

// ---------------------------------------------------------------------------
// m97-style 128x128 f16 GEMM: C = A(MxK) * Bt(NxK)^T.  grid (M/128, N/128).
// ---------------------------------------------------------------------------
template <int OUT_F16>
__global__ __launch_bounds__(256) void gemm_k(const half_t* __restrict__ A,
                                              const half_t* __restrict__ Bt,
                                              void* __restrict__ C, int K, int ldc) {
    __shared__ half_t As[128 * 32];
    __shared__ half_t Bs[128 * 32];
    const int tid = threadIdx.x, lane = tid & 63, w = tid >> 6;
    const int lo = lane & 15, hi = lane >> 4;
    const int wr = w >> 1, wc = w & 1;
    const long tm = blockIdx.x, tn = blockIdx.y;
    const half_t* Ab = A + tm * 128 * (long)K;
    const half_t* Bb = Bt + tn * 128 * (long)K;
    f32x4 acc[4][4] = {};
    const int rl = (lane >> 2);       // 0..15 row-within-16
    const int kl = (lane & 3) * 8;    // 0/8/16/24
    for (int k0 = 0; k0 < K; k0 += 32) {
#pragma unroll
        for (int t = 0; t < 2; ++t) {
            int seg = w * 2 + t;      // 0..7, 16 rows each
            int r = seg * 16 + rl;
            gload16(As + seg * 512, Ab + (long)r * K + k0 + kl);
            gload16(Bs + seg * 512, Bb + (long)r * K + k0 + kl);
        }
        __syncthreads();  // compiler drains vmcnt before s_barrier
        half8 af[4], bf[4];
#pragma unroll
        for (int m = 0; m < 4; ++m)
            af[m] = *(const half8*)(As + (wr * 64 + m * 16 + lo) * 32 + hi * 8);
#pragma unroll
        for (int n = 0; n < 4; ++n)
            bf[n] = *(const half8*)(Bs + (wc * 64 + n * 16 + lo) * 32 + hi * 8);
#pragma unroll
        for (int m = 0; m < 4; ++m)
#pragma unroll
            for (int n = 0; n < 4; ++n) acc[m][n] = MFMA16(af[m], bf[n], acc[m][n]);
        __syncthreads();
    }
#pragma unroll
    for (int m = 0; m < 4; ++m)
#pragma unroll
        for (int n = 0; n < 4; ++n)
#pragma unroll
            for (int e = 0; e < 4; ++e) {
                long row = tm * 128 + wr * 64 + m * 16 + hi * 4 + e;
                long col = tn * 128 + wc * 64 + n * 16 + lo;
                if (OUT_F16)
                    ((half_t*)C)[row * ldc + col] = (half_t)acc[m][n][e];
                else
                    ((float*)C)[row * ldc + col] = acc[m][n][e];
            }
}

// ---------------------------------------------------------------------------
// Causal depthwise conv (KW=4) + SiLU over mixed (B,S,8320) channels 0..8191.
// grid: (32 channel-blocks, B*32 s-chunks of 128)
// ---------------------------------------------------------------------------
__global__ __launch_bounds__(256) void conv_silu_k(const half_t* __restrict__ mixedH,
                                                   const float* __restrict__ conv_w,
                                                   half_t* __restrict__ qb,
                                                   half_t* __restrict__ kb,
                                                   half_t* __restrict__ vb) {
    int ch = blockIdx.x * 256 + threadIdx.x;     // 0..8191 (== conv channel)
    int b = blockIdx.y >> 5, sc = blockIdx.y & 31;
    int s0 = sc * 128;
    half_t* dptr;
    long dstr;
    if (ch < 2048)      { dptr = qb + ch;          dstr = 2048; }
    else if (ch < 4096) { dptr = kb + (ch - 2048); dstr = 2048; }
    else                { dptr = vb + (ch - 4096); dstr = 4096; }
    float w0 = conv_w[ch * 4 + 0], w1 = conv_w[ch * 4 + 1];
    float w2 = conv_w[ch * 4 + 2], w3 = conv_w[ch * 4 + 3];
    const half_t* src = mixedH + (long)b * 4096 * 8320 + ch;
    float x0 = (s0 >= 3) ? (float)src[(long)(s0 - 3) * 8320] : 0.f;
    float x1 = (s0 >= 2) ? (float)src[(long)(s0 - 2) * 8320] : 0.f;
    float x2 = (s0 >= 1) ? (float)src[(long)(s0 - 1) * 8320] : 0.f;
    for (int s = s0; s < s0 + 128; ++s) {
        float x3 = (float)src[(long)s * 8320];
        float y = w0 * x0 + w1 * x1 + w2 * x2 + w3 * x3;
        y = y / (1.f + expf(-y));  // silu
        dptr[((long)b * 4096 + s) * dstr] = (half_t)y;
        x0 = x1; x1 = x2; x2 = x3;
    }
}

// ---------------------------------------------------------------------------
// beta = sigmoid(b), g = -exp(A_log)*softplus(a+dt_bias), per-chunk cumsum.
// grid: B*64 blocks (one per (b, chunk)); ba at mixedH cols 8192..8255.
// ---------------------------------------------------------------------------
__global__ __launch_bounds__(256) void gate_beta_k(const half_t* __restrict__ mixedH,
                                                   const float* __restrict__ A_log,
                                                   const float* __restrict__ dt_bias,
                                                   float* __restrict__ beta,
                                                   float* __restrict__ gcum) {
    __shared__ float gs[32][64];
    int b = blockIdx.x >> 6, c = blockIdx.x & 63;
    for (int idx = threadIdx.x; idx < 2048; idx += 256) {
        int vh = idx & 31, i = idx >> 5;
        int kh = vh >> 1, j = vh & 1;
        long row = ((long)b * 4096 + c * 64 + i) * 8320 + 8192 + kh * 4;
        float bb = (float)mixedH[row + j];
        float aa = (float)mixedH[row + 2 + j];
        beta[((long)b * 4096 + c * 64 + i) * 32 + vh] = 1.f / (1.f + expf(-bb));
        float x = aa + dt_bias[vh];
        float sp = (x > 15.f) ? x : log1pf(expf(x));
        gs[vh][i] = -expf(A_log[vh]) * sp;
    }
    __syncthreads();
    if (threadIdx.x < 32) {
        int vh = threadIdx.x;
        float cum = 0.f;
        float* gout = gcum + ((long)(b * 32 + vh)) * 4096 + c * 64;
        for (int i = 0; i < 64; ++i) { cum += gs[vh][i]; gout[i] = cum; }
    }
}

// ---------------------------------------------------------------------------
// l2norm rows of 128 (in-place, f16). q rows get extra 1/sqrt(128).
// grid: 65536 blocks * 4 waves; rows 0..131071 = q, 131072..262143 = k.
// ---------------------------------------------------------------------------
__global__ __launch_bounds__(256) void l2norm_k(half_t* __restrict__ qb,
                                                half_t* __restrict__ kb) {
    int w = threadIdx.x >> 6, lane = threadIdx.x & 63;
    long rid = (long)blockIdx.x * 4 + w;
    half_t* base;
    float sc;
    if (rid < 131072) { base = qb + rid * 128; sc = 0.08838834764831845f; }
    else              { base = kb + (rid - 131072) * 128; sc = 1.f; }
    half2_t hv = *(half2_t*)(base + lane * 2);
    float f0 = (float)hv[0], f1 = (float)hv[1];
    float ss = f0 * f0 + f1 * f1;
#pragma unroll
    for (int off = 32; off; off >>= 1) ss += __shfl_xor(ss, off);
    float r = rsqrtf(ss + 1e-6f) * sc;
    half2_t o; o[0] = (half_t)(f0 * r); o[1] = (half_t)(f1 * r);
    *(half2_t*)(base + lane * 2) = o;
}

// ---------------------------------------------------------------------------
// Phase 1: per (b,vh,chunk): A, T=(I-A)^-1, attn, v_t, -kc.  grid 4096.
// ---------------------------------------------------------------------------
__global__ __launch_bounds__(256) void phase1_k(const half_t* __restrict__ qb,
                                                const half_t* __restrict__ kb,
                                                const half_t* __restrict__ vb,
                                                const float* __restrict__ beta,
                                                const float* __restrict__ gcum,
                                                half_t* __restrict__ attnW,
                                                half_t* __restrict__ vtW,
                                                half_t* __restrict__ kcW) {
    __shared__ float AT[64 * 64];       // swizzled rows (256 B); A then T in-place
    __shared__ half_t XT[256 * 64];     // rows 0..127 = (v*beta)^T, 128..255 = (k*beta*e^g)^T
    __shared__ float gcS[64], betaS[64], egS[64];
    int blk = blockIdx.x;
    int c = blk & 63, vh = (blk >> 6) & 31, b = blk >> 11;
    int kh = vh >> 1;
    int tid = threadIdx.x, lane = tid & 63, w = tid >> 6, lo = lane & 15, hi = lane >> 4;
    long rowbase = (long)b * 4096 + c * 64;
    if (tid < 64) {
        float g = gcum[((long)(b * 32 + vh)) * 4096 + c * 64 + tid];
        gcS[tid] = g; egS[tid] = expf(g);
        betaS[tid] = beta[(rowbase + tid) * 32 + vh];
    }
    // G = kn@kn^T, attn_raw = qn@kn^T via global-gather fragments
    const half_t* kR = kb + rowbase * 2048 + kh * 128;
    const half_t* qR = qb + rowbase * 2048 + kh * 128;
    f32x4 accG[4] = {}, accA[4] = {};
#pragma unroll
    for (int kt = 0; kt < 4; ++kt) {
        half8 ak = *(const half8*)(kR + (long)(w * 16 + lo) * 2048 + kt * 32 + hi * 8);
        half8 aq = *(const half8*)(qR + (long)(w * 16 + lo) * 2048 + kt * 32 + hi * 8);
#pragma unroll
        for (int n = 0; n < 4; ++n) {
            half8 bk = *(const half8*)(kR + (long)(n * 16 + lo) * 2048 + kt * 32 + hi * 8);
            accG[n] = MFMA16(ak, bk, accG[n]);
            accA[n] = MFMA16(aq, bk, accA[n]);
        }
    }
    __syncthreads();  // gcS/betaS ready
    half_t* attnB = attnW + (long)blk * 4096;
#pragma unroll
    for (int n = 0; n < 4; ++n)
#pragma unroll
        for (int e = 0; e < 4; ++e) {
            int i = w * 16 + hi * 4 + e;
            int j = n * 16 + lo;
            float dec = (j < i) ? expf(gcS[i] - gcS[j]) : 0.f;
            float av = (j < i) ? (-betaS[i] * accG[n][e] * dec) : (j == i ? 1.f : 0.f);
            at_wr(AT, i, j, av);
            attnB[(long)i * 64 + j] = (half_t)((j < i) ? accA[n][e] * dec : 0.f);
        }
    __syncthreads();
    if (w == 0) {
        // forward substitution, in place: T[i][j] = d_ij + sum_{p<i} A[i][p]*T[p][j]
        int j = lane;
        for (int i = 1; i < 64; ++i) {
            float acc2 = 0.f;
            for (int p = 0; p < i; ++p) acc2 += at_rd(AT, i, p) * at_rd(AT, p, j);
            at_wr(AT, i, j, (j == i) ? 1.f : acc2);
        }
    } else {
        // build XT (transposed operands), overlapped with the solve
        for (int idx = tid - 64; idx < 4096; idx += 192) {
            int p = idx >> 6, dp = idx & 63;
            float bb = betaS[p], be = betaS[p] * egS[p];
            half2_t vv = *(const half2_t*)(vb + (rowbase + p) * 4096 + vh * 128 + dp * 2);
            half2_t kk = *(const half2_t*)(kb + (rowbase + p) * 2048 + kh * 128 + dp * 2);
            w64(XT, dp * 2,       p, (float)vv[0] * bb);
            w64(XT, dp * 2 + 1,   p, (float)vv[1] * bb);
            w64(XT, 128 + dp * 2,     p, (float)kk[0] * be);
            w64(XT, 128 + dp * 2 + 1, p, (float)kk[1] * be);
        }
    }
    __syncthreads();
    // [v_t | kc] = T @ [v*beta | k*beta*e^g]  (wave w -> output cols 64w..64w+63)
    f32x4 accO[4][4] = {};
#pragma unroll
    for (int kt = 0; kt < 2; ++kt) {
        half8 tf[4];
#pragma unroll
        for (int m = 0; m < 4; ++m) {
            int r = m * 16 + lo;
            int b0 = (kt * 32 + hi * 8) * 4;
            f32x4 x0 = *(const f32x4*)((const char*)AT + r * 256 + (b0 ^ ((r & 7) << 4)));
            f32x4 x1 = *(const f32x4*)((const char*)AT + r * 256 + ((b0 + 16) ^ ((r & 7) << 4)));
            half8 h;
            h[0] = (half_t)x0[0]; h[1] = (half_t)x0[1]; h[2] = (half_t)x0[2]; h[3] = (half_t)x0[3];
            h[4] = (half_t)x1[0]; h[5] = (half_t)x1[1]; h[6] = (half_t)x1[2]; h[7] = (half_t)x1[3];
            tf[m] = h;
        }
#pragma unroll
        for (int n = 0; n < 4; ++n) {
            half8 bx = frag64(XT, w * 64 + n * 16 + lo, kt * 32 + hi * 8);
#pragma unroll
            for (int m = 0; m < 4; ++m) accO[m][n] = MFMA16(tf[m], bx, accO[m][n]);
        }
    }
    long ob = (long)blk * 8192;
#pragma unroll
    for (int m = 0; m < 4; ++m)
#pragma unroll
        for (int n = 0; n < 4; ++n)
#pragma unroll
            for (int e = 0; e < 4; ++e) {
                int i = m * 16 + hi * 4 + e;
                int dc = w * 64 + n * 16 + lo;
                float v = accO[m][n][e];
                if (dc < 128) vtW[ob + (long)i * 128 + dc] = (half_t)v;
                else          kcW[ob + (long)i * 128 + dc - 128] = (half_t)(-v);  // store -kc
            }
}

// ---------------------------------------------------------------------------
// Phase 2: sequential chunk scan per (b,vh). State^T f16 in LDS, MFMA matmuls.
// grid 64.
// ---------------------------------------------------------------------------
__global__ __launch_bounds__(256) void phase2_k(const half_t* __restrict__ qb,
                                                const half_t* __restrict__ kb,
                                                const float* __restrict__ gcum,
                                                const half_t* __restrict__ attnW,
                                                const half_t* __restrict__ vtW,
                                                const half_t* __restrict__ kcW,
                                                half_t* __restrict__ coreH) {
    __shared__ half_t SH[128 * 128];   // state^T: SH[v][d], swizzled rows of 256 B
    __shared__ half_t vnT[128 * 64];   // v_new^T, swizzled rows of 128 B
    __shared__ half_t kdT[128 * 64];   // (k*e^{gl-g})^T, swizzled
    int blk = blockIdx.x;
    int vh = blk & 31, b = blk >> 5, kh = vh >> 1;
    int tid = threadIdx.x, lane = tid & 63, w = tid >> 6, lo = lane & 15, hi = lane >> 4;
    for (int idx = tid; idx < 128 * 128; idx += 256) SH[idx] = (half_t)0.f;
    __syncthreads();
    const float* gbase = gcum + (long)blk * 4096;
    for (int c = 0; c < 64; ++c) {
        long rowbase = (long)b * 4096 + c * 64;
        long pb = (long)blk * 64 + c;
        const half_t* kcG = kcW + pb * 8192;   // holds -kc
        const half_t* vtG = vtW + pb * 8192;
        const half_t* atG = attnW + pb * 4096;
        const float* gp = gbase + c * 64;
        float g63 = gp[63];
        // ---- v_new = v_t - kc@S  (wave w -> v-cols [32w, 32w+32)) ----
        f32x4 accV[4][2];
#pragma unroll
        for (int m = 0; m < 4; ++m)
#pragma unroll
            for (int n = 0; n < 2; ++n)
#pragma unroll
                for (int e = 0; e < 4; ++e)
                    accV[m][n][e] = (float)vtG[(long)(m * 16 + hi * 4 + e) * 128 +
                                               (w * 32 + n * 16 + lo)];
#pragma unroll
        for (int kt = 0; kt < 4; ++kt) {
            half8 bS0 = frag128(SH, w * 32 + lo,      kt * 32 + hi * 8);
            half8 bS1 = frag128(SH, w * 32 + 16 + lo, kt * 32 + hi * 8);
#pragma unroll
            for (int m = 0; m < 4; ++m) {
                half8 a = *(const half8*)(kcG + (long)(m * 16 + lo) * 128 + kt * 32 + hi * 8);
                accV[m][0] = MFMA16(a, bS0, accV[m][0]);
                accV[m][1] = MFMA16(a, bS1, accV[m][1]);
            }
        }
#pragma unroll
        for (int m = 0; m < 4; ++m)
#pragma unroll
            for (int n = 0; n < 2; ++n) {
                int j = w * 32 + n * 16 + lo;
                int i0 = m * 16 + hi * 4;
                half2_t p01, p23;
                p01[0] = (half_t)accV[m][n][0]; p01[1] = (half_t)accV[m][n][1];
                p23[0] = (half_t)accV[m][n][2]; p23[1] = (half_t)accV[m][n][3];
                char* bp = (char*)vnT + j * 128;
                *(half2_t*)(bp + ((i0 * 2) ^ ((j & 7) << 4))) = p01;
                *(half2_t*)(bp + ((i0 * 2 + 4) ^ ((j & 7) << 4))) = p23;
            }
        __syncthreads();
        // ---- out = (qn*e^g)@S + attn@v_new ----
        float egm[4];
#pragma unroll
        for (int m = 0; m < 4; ++m) egm[m] = expf(gp[m * 16 + lo]);
        f32x4 accO[4][2] = {};
#pragma unroll
        for (int kt = 0; kt < 4; ++kt) {
            half8 bS0 = frag128(SH, w * 32 + lo,      kt * 32 + hi * 8);
            half8 bS1 = frag128(SH, w * 32 + 16 + lo, kt * 32 + hi * 8);
#pragma unroll
            for (int m = 0; m < 4; ++m) {
                half8 qf = *(const half8*)(qb + (rowbase + m * 16 + lo) * 2048 + kh * 128 +
                                           kt * 32 + hi * 8);
                half8 a;
#pragma unroll
                for (int e2 = 0; e2 < 8; ++e2) a[e2] = (half_t)((float)qf[e2] * egm[m]);
                accO[m][0] = MFMA16(a, bS0, accO[m][0]);
                accO[m][1] = MFMA16(a, bS1, accO[m][1]);
            }
        }
#pragma unroll
        for (int kt2 = 0; kt2 < 2; ++kt2) {
            half8 bV0 = frag64(vnT, w * 32 + lo,      kt2 * 32 + hi * 8);
            half8 bV1 = frag64(vnT, w * 32 + 16 + lo, kt2 * 32 + hi * 8);
#pragma unroll
            for (int m = 0; m < 4; ++m) {
                half8 a = *(const half8*)(atG + (long)(m * 16 + lo) * 64 + kt2 * 32 + hi * 8);
                accO[m][0] = MFMA16(a, bV0, accO[m][0]);
                accO[m][1] = MFMA16(a, bV1, accO[m][1]);
            }
        }
#pragma unroll
        for (int m = 0; m < 4; ++m)
#pragma unroll
            for (int n = 0; n < 2; ++n)
#pragma unroll
                for (int e = 0; e < 4; ++e)
                    coreH[(rowbase + m * 16 + hi * 4 + e) * 4096 + vh * 128 +
                          (w * 32 + n * 16 + lo)] = (half_t)accO[m][n][e];
        __syncthreads();
        // ---- build kdT[d][i] = kn[i][d] * exp(g63 - g_i) ----
        for (int idx = tid; idx < 4096; idx += 256) {
            int p = idx >> 6, dp = idx & 63;
            float ek = expf(g63 - gp[p]);
            half2_t kk = *(const half2_t*)(kb + (rowbase + p) * 2048 + kh * 128 + dp * 2);
            w64(kdT, dp * 2,     p, (float)kk[0] * ek);
            w64(kdT, dp * 2 + 1, p, (float)kk[1] * ek);
        }
        __syncthreads();
        // ---- state update: S^T = e^{g63}*S^T + v_new^T @ kd ----
        float egl = expf(g63);
        f32x4 accU[2][8] = {};
#pragma unroll
        for (int kt2 = 0; kt2 < 2; ++kt2) {
            half8 a0 = frag64(vnT, w * 32 + lo,      kt2 * 32 + hi * 8);
            half8 a1 = frag64(vnT, w * 32 + 16 + lo, kt2 * 32 + hi * 8);
#pragma unroll
            for (int dn = 0; dn < 8; ++dn) {
                half8 bx = frag64(kdT, dn * 16 + lo, kt2 * 32 + hi * 8);
                accU[0][dn] = MFMA16(a0, bx, accU[0][dn]);
                accU[1][dn] = MFMA16(a1, bx, accU[1][dn]);
            }
        }
#pragma unroll
        for (int jm = 0; jm < 2; ++jm)
#pragma unroll
            for (int dn = 0; dn < 8; ++dn)
#pragma unroll
                for (int e = 0; e < 4; ++e) {
                    int j = w * 32 + jm * 16 + hi * 4 + e;
                    int d = dn * 16 + lo;
                    char* p = (char*)SH + j * 256 + ((d * 2) ^ ((j & 7) << 4));
                    float old = (float)*(half_t*)p;
                    *(half_t*)p = (half_t)(old * egl + accU[jm][dn][e]);
                }
        __syncthreads();
    }
}

// ---------------------------------------------------------------------------
// Gated RMSNorm + silu(z) gate, IN-PLACE on coreH. One wave per (b,s,vh) row.
// grid: 65536 (= B*S*HV/4 waves).
// ---------------------------------------------------------------------------
__global__ __launch_bounds__(256) void normgate_k(half_t* __restrict__ coreH,
                                                  const half_t* __restrict__ zH,
                                                  const float* __restrict__ norm_w) {
    int w = threadIdx.x >> 6, lane = threadIdx.x & 63;
    long rid = (long)blockIdx.x * 4 + w;  // < 262144
    long bs = rid >> 5;
    int vh = rid & 31;
    half_t* cr = coreH + bs * 4096 + vh * 128;
    half2_t cv = *(half2_t*)(cr + lane * 2);
    float f0 = (float)cv[0], f1 = (float)cv[1];
    float ss = f0 * f0 + f1 * f1;
#pragma unroll
    for (int off = 32; off; off >>= 1) ss += __shfl_xor(ss, off);
    float rs = rsqrtf(ss * (1.f / 128.f) + 1e-6f);
    half2_t zz = *(const half2_t*)(zH + bs * 4096 + vh * 128 + lane * 2);
    float z0 = (float)zz[0], z1 = (float)zz[1];
    float s0 = z0 / (1.f + expf(-z0)), s1 = z1 / (1.f + expf(-z1));
    float w0 = norm_w[lane * 2], w1 = norm_w[lane * 2 + 1];
    half2_t o;
    o[0] = (half_t)(f0 * rs * w0 * s0);
    o[1] = (half_t)(f1 * rs * w1 * s1);
    *(half2_t*)(cr + lane * 2) = o;
}

// ---------------------------------------------------------------------------
// Host launcher.  Workspace layout (MiB offsets), hand-aliased, peak 370 MiB:
//   [0,32)    qb          (conv..phase2)   | overlay: hiddenH (cast..gemm1)
//   [32,64)   kb          (conv..phase2)   | overlay: W1T head
//   [64,128)  vb          (conv..phase1)   | overlay: W1T tail [64,81);
//                                            later coreH (phase2..gemm2)
//   [128,129) betaB   [129,130) gcum
//   [130,146) WoT         (build..gemm2)
//   [146,210) zH          (gemm1b..normgate)
//   [210,340) mixedH      (gemm1a..gate)   | overlay after: attnW [210,242),
//   [340,370)                                vtW [242,306), kcW [306,370)
// ---------------------------------------------------------------------------
extern "C" void kernel_launch(void* const* d_in, const int* in_sizes, int n_in,
                              void* d_out, int out_size, void* d_ws, size_t ws_size,
                              hipStream_t stream) {
    const float* hidden  = (const float*)d_in[0];
    const float* W_qkvz  = (const float*)d_in[1];
    const float* W_ba    = (const float*)d_in[2];
    const float* conv_w  = (const float*)d_in[3];
    const float* A_log   = (const float*)d_in[4];
    const float* dt_bias = (const float*)d_in[5];
    const float* norm_w  = (const float*)d_in[6];
    const float* W_out   = (const float*)d_in[7];
    float* out = (float*)d_out;

    char* ws = (char*)d_ws;
    const size_t MB = 1ull << 20;
    half_t* qb      = (half_t*)(ws + 0);
    half_t* kb      = (half_t*)(ws + 32 * MB);
    half_t* vb      = (half_t*)(ws + 64 * MB);
    float*  betaB   = (float*) (ws + 128 * MB);
    float*  gcum    = (float*) (ws + 129 * MB);
    half_t* WoT     = (half_t*)(ws + 130 * MB);
    half_t* zH      = (half_t*)(ws + 146 * MB);
    half_t* mixedH  = (half_t*)(ws + 210 * MB);
    half_t* attnW   = (half_t*)(ws + 210 * MB);  // overlays dead mixedH
    half_t* vtW     = (half_t*)(ws + 242 * MB);
    half_t* kcW     = (half_t*)(ws + 306 * MB);
    half_t* hiddenH = (half_t*)(ws + 0);         // overlays not-yet-written qb
    half_t* W1T     = (half_t*)(ws + 32 * MB);   // overlays kb + head of vb
    half_t* coreH   = (half_t*)(ws + 64 * MB);   // overlays dead vb
    (void)ws_size; (void)in_sizes; (void)n_in; (void)out_size;

    // 1. casts / transposes
    cast_h_k<<<16384, 256, 0, stream>>>(hidden, hiddenH);
    build_w1t_k<<<dim3(388, 64), 256, 0, stream>>>(W_qkvz, W_ba, W1T);
    build_wot_k<<<dim3(64, 128), 256, 0, stream>>>(W_out, WoT);
    // 2. fused projection, split: qkv+ba (N=8320) then z (N=4096); K=2048
    gemm_k<1><<<dim3(64, 65), 256, 0, stream>>>(hiddenH, W1T, mixedH, 2048, 8320);
    gemm_k<1><<<dim3(64, 32), 256, 0, stream>>>(hiddenH, W1T + (size_t)8320 * 2048, zH,
                                                2048, 4096);
    // 3. conv + silu ; gates ; l2norm
    conv_silu_k<<<dim3(32, 64), 256, 0, stream>>>(mixedH, conv_w, qb, kb, vb);
    gate_beta_k<<<128, 256, 0, stream>>>(mixedH, A_log, dt_bias, betaB, gcum);
    l2norm_k<<<65536, 256, 0, stream>>>(qb, kb);
    // 4. delta-rule core
    phase1_k<<<4096, 256, 0, stream>>>(qb, kb, vb, betaB, gcum, attnW, vtW, kcW);
    phase2_k<<<64, 256, 0, stream>>>(qb, kb, gcum, attnW, vtW, kcW, coreH);
    // 5. gated RMSNorm (in-place) + output projection (M=8192, N=2048, K=4096)
    normgate_k<<<65536, 256, 0, stream>>>(coreH, zH, norm_w);
    gemm_k<0><<<dim3(64, 16), 256, 0, stream>>>(coreH, WoT, out, 4096, 2048);
}

// Round 3
// 1584.214 us; speedup vs baseline: 1.5574x; 1.5574x over previous
//
#include <hip/hip_runtime.h>
#include <cstdint>
#include <cstddef>

// ---------------------------------------------------------------------------
// Qwen3.5 GatedDeltaNet forward, MI355X (gfx950), f16-MFMA implementation.
// B=2, S=4096, H=2048, HK=16, HV=32, DK=DV=128, KW=4, CS=64.
// Workspace peak: 370 MiB (hand-aliased layout, see kernel_launch).
// R2: phase2 split 4x across DV (grid 64 -> 256, 1 block/CU), register
//     double-buffered operand prefetch, S-fragment reuse, 3 barriers/chunk.
// ---------------------------------------------------------------------------

typedef _Float16 half_t;
typedef _Float16 half2_t __attribute__((ext_vector_type(2)));
typedef _Float16 half4_t __attribute__((ext_vector_type(4)));
typedef _Float16 half8   __attribute__((ext_vector_type(8)));
typedef float    f32x4   __attribute__((ext_vector_type(4)));

#define MFMA16(a, b, c) __builtin_amdgcn_mfma_f32_16x16x32_f16((a), (b), (c), 0, 0, 0)

#define AS1 __attribute__((address_space(1)))
#define AS3 __attribute__((address_space(3)))

// async global->LDS, 16B per lane; LDS dest is wave-uniform base + lane*16.
__device__ __forceinline__ void gload16(void* lds, const void* g) {
    __builtin_amdgcn_global_load_lds((AS1 void*)(g), (AS3 void*)(lds), 16, 0, 0);
}

// ---- swizzled-LDS access helpers (XOR byte-bits 4..6 with row&7) ----------
// f32 array, rows of 64 floats (256 B). Used for A/T (in-place solve).
__device__ __forceinline__ float at_rd(const float* AT, int i, int j) {
    return *(const float*)((const char*)AT + i * 256 + ((j * 4) ^ ((i & 7) << 4)));
}
__device__ __forceinline__ void at_wr(float* AT, int i, int j, float v) {
    *(float*)((char*)AT + i * 256 + ((j * 4) ^ ((i & 7) << 4))) = v;
}
// f16 array, rows of 64 halfs (128 B): XT, vnT, kdT.
__device__ __forceinline__ half8 frag64(const half_t* base, int row, int koff) {
    return *(const half8*)((const char*)base + row * 128 + ((koff * 2) ^ ((row & 7) << 4)));
}
__device__ __forceinline__ void w64(half_t* base, int row, int col, float v) {
    *(half_t*)((char*)base + row * 128 + ((col * 2) ^ ((row & 7) << 4))) = (half_t)v;
}
// f16 array, rows of 128 halfs (256 B): SHs (state^T slice), phase1 XT pairing.
__device__ __forceinline__ half8 frag128(const half_t* base, int row, int koff) {
    return *(const half8*)((const char*)base + row * 256 + ((koff * 2) ^ ((row & 7) << 4)));
}

// ---------------------------------------------------------------------------
// Cast / transpose prep kernels
// ---------------------------------------------------------------------------
__global__ __launch_bounds__(256) void cast_h_k(const float* __restrict__ src,
                                                half_t* __restrict__ dst) {
    long i = (long)blockIdx.x * 256 + threadIdx.x;  // processes 4 elems
    f32x4 v = *(const f32x4*)(src + i * 4);
    half4_t h;
    h[0] = (half_t)v[0]; h[1] = (half_t)v[1]; h[2] = (half_t)v[2]; h[3] = (half_t)v[3];
    *(half4_t*)(dst + i * 4) = h;
}

// Column-permuted W1T[n][k]:
//   n in [0,2048)     : q flat   (kh=n>>7, d=n&127)       -> Wq col kh*768+d
//   n in [2048,4096)  : k flat                             -> Wq col kh*768+128+d
//   n in [4096,8192)  : v flat   (vh=(n-4096)>>7)          -> Wq col kh*768+256+jj*128+d
//   n in [8192,8256)  : ba                                 -> Wba col n-8192
//   n in [8256,8320)  : zero pad
//   n in [8320,12416) : z flat   (vh=(n-8320)>>7)          -> Wq col kh*768+512+jj*128+d
__global__ __launch_bounds__(256) void build_w1t_k(const float* __restrict__ Wq,
                                                   const float* __restrict__ Wba,
                                                   half_t* __restrict__ W1T) {
    __shared__ half_t tile[32][33];
    int n0 = blockIdx.x * 32, k0 = blockIdx.y * 32;
    int tx = threadIdx.x & 31, ty = threadIdx.x >> 5;
#pragma unroll
    for (int t = 0; t < 4; ++t) {
        int k = k0 + ty + t * 8, n = n0 + tx;
        float v = 0.f;
        if (n < 2048) {
            int kh = n >> 7, d = n & 127;
            v = Wq[(long)k * 12288 + kh * 768 + d];
        } else if (n < 4096) {
            int n2 = n - 2048; int kh = n2 >> 7, d = n2 & 127;
            v = Wq[(long)k * 12288 + kh * 768 + 128 + d];
        } else if (n < 8192) {
            int n3 = n - 4096; int vh = n3 >> 7, d = n3 & 127;
            int kh = vh >> 1, jj = vh & 1;
            v = Wq[(long)k * 12288 + kh * 768 + 256 + jj * 128 + d];
        } else if (n < 8256) {
            v = Wba[(long)k * 64 + (n - 8192)];
        } else if (n >= 8320) {
            int n4 = n - 8320; int vh = n4 >> 7, d = n4 & 127;
            int kh = vh >> 1, jj = vh & 1;
            v = Wq[(long)k * 12288 + kh * 768 + 512 + jj * 128 + d];
        }
        tile[ty + t * 8][tx] = (half_t)v;
    }
    __syncthreads();
#pragma unroll
    for (int t = 0; t < 4; ++t) {
        int n = n0 + ty + t * 8, k = k0 + tx;
        W1T[(long)n * 2048 + k] = tile[tx][ty + t * 8];
    }
}

// WoT[n][k] = W_out[k][n]; n < 2048, k < 4096
__global__ __launch_bounds__(256) void build_wot_k(const float* __restrict__ Wo,
                                                   half_t* __restrict__ WoT) {
    __shared__ half_t tile[32][33];
    int n0 = blockIdx.x * 32, k0 = blockIdx.y * 32;
    int tx = threadIdx.x & 31, ty = threadIdx.x >> 5;
#pragma unroll
    for (int t = 0; t < 4; ++t) {
        int k = k0 + ty + t * 8, n = n0 + tx;
        tile[ty + t * 8][tx] = (half_t)Wo[(long)k * 2048 + n];
    }
    __syncthreads();
#pragma unroll
    for (int t = 0; t < 4; ++t) {
        int n = n0 + ty + t * 8, k = k0 + tx;
        WoT[(long)n * 4096 + k] = tile[tx][ty + t * 8];
    }
}

// ---------------------------------------------------------------------------
// m97-style 128x128 f16 GEMM: C = A(MxK) * Bt(NxK)^T.  grid (M/128, N/128).
// ---------------------------------------------------------------------------
template <int OUT_F16>
__global__ __launch_bounds__(256) void gemm_k(const half_t* __restrict__ A,
                                              const half_t* __restrict__ Bt,
                                              void* __restrict__ C, int K, int ldc) {
    __shared__ half_t As[128 * 32];
    __shared__ half_t Bs[128 * 32];
    const int tid = threadIdx.x, lane = tid & 63, w = tid >> 6;
    const int lo = lane & 15, hi = lane >> 4;
    const int wr = w >> 1, wc = w & 1;
    const long tm = blockIdx.x, tn = blockIdx.y;
    const half_t* Ab = A + tm * 128 * (long)K;
    const half_t* Bb = Bt + tn * 128 * (long)K;
    f32x4 acc[4][4] = {};
    const int rl = (lane >> 2);       // 0..15 row-within-16
    const int kl = (lane & 3) * 8;    // 0/8/16/24
    for (int k0 = 0; k0 < K; k0 += 32) {
#pragma unroll
        for (int t = 0; t < 2; ++t) {
            int seg = w * 2 + t;      // 0..7, 16 rows each
            int r = seg * 16 + rl;
            gload16(As + seg * 512, Ab + (long)r * K + k0 + kl);
            gload16(Bs + seg * 512, Bb + (long)r * K + k0 + kl);
        }
        __syncthreads();  // compiler drains vmcnt before s_barrier
        half8 af[4], bf[4];
#pragma unroll
        for (int m = 0; m < 4; ++m)
            af[m] = *(const half8*)(As + (wr * 64 + m * 16 + lo) * 32 + hi * 8);
#pragma unroll
        for (int n = 0; n < 4; ++n)
            bf[n] = *(const half8*)(Bs + (wc * 64 + n * 16 + lo) * 32 + hi * 8);
#pragma unroll
        for (int m = 0; m < 4; ++m)
#pragma unroll
            for (int n = 0; n < 4; ++n) acc[m][n] = MFMA16(af[m], bf[n], acc[m][n]);
        __syncthreads();
    }
#pragma unroll
    for (int m = 0; m < 4; ++m)
#pragma unroll
        for (int n = 0; n < 4; ++n)
#pragma unroll
            for (int e = 0; e < 4; ++e) {
                long row = tm * 128 + wr * 64 + m * 16 + hi * 4 + e;
                long col = tn * 128 + wc * 64 + n * 16 + lo;
                if (OUT_F16)
                    ((half_t*)C)[row * ldc + col] = (half_t)acc[m][n][e];
                else
                    ((float*)C)[row * ldc + col] = acc[m][n][e];
            }
}

// ---------------------------------------------------------------------------
// Causal depthwise conv (KW=4) + SiLU over mixed (B,S,8320) channels 0..8191.
// grid: (32 channel-blocks, B*32 s-chunks of 128)
// ---------------------------------------------------------------------------
__global__ __launch_bounds__(256) void conv_silu_k(const half_t* __restrict__ mixedH,
                                                   const float* __restrict__ conv_w,
                                                   half_t* __restrict__ qb,
                                                   half_t* __restrict__ kb,
                                                   half_t* __restrict__ vb) {
    int ch = blockIdx.x * 256 + threadIdx.x;     // 0..8191 (== conv channel)
    int b = blockIdx.y >> 5, sc = blockIdx.y & 31;
    int s0 = sc * 128;
    half_t* dptr;
    long dstr;
    if (ch < 2048)      { dptr = qb + ch;          dstr = 2048; }
    else if (ch < 4096) { dptr = kb + (ch - 2048); dstr = 2048; }
    else                { dptr = vb + (ch - 4096); dstr = 4096; }
    float w0 = conv_w[ch * 4 + 0], w1 = conv_w[ch * 4 + 1];
    float w2 = conv_w[ch * 4 + 2], w3 = conv_w[ch * 4 + 3];
    const half_t* src = mixedH + (long)b * 4096 * 8320 + ch;
    float x0 = (s0 >= 3) ? (float)src[(long)(s0 - 3) * 8320] : 0.f;
    float x1 = (s0 >= 2) ? (float)src[(long)(s0 - 2) * 8320] : 0.f;
    float x2 = (s0 >= 1) ? (float)src[(long)(s0 - 1) * 8320] : 0.f;
    for (int s = s0; s < s0 + 128; ++s) {
        float x3 = (float)src[(long)s * 8320];
        float y = w0 * x0 + w1 * x1 + w2 * x2 + w3 * x3;
        y = y / (1.f + expf(-y));  // silu
        dptr[((long)b * 4096 + s) * dstr] = (half_t)y;
        x0 = x1; x1 = x2; x2 = x3;
    }
}

// ---------------------------------------------------------------------------
// beta = sigmoid(b), g = -exp(A_log)*softplus(a+dt_bias), per-chunk cumsum.
// grid: B*64 blocks (one per (b, chunk)); ba at mixedH cols 8192..8255.
// ---------------------------------------------------------------------------
__global__ __launch_bounds__(256) void gate_beta_k(const half_t* __restrict__ mixedH,
                                                   const float* __restrict__ A_log,
                                                   const float* __restrict__ dt_bias,
                                                   float* __restrict__ beta,
                                                   float* __restrict__ gcum) {
    __shared__ float gs[32][64];
    int b = blockIdx.x >> 6, c = blockIdx.x & 63;
    for (int idx = threadIdx.x; idx < 2048; idx += 256) {
        int vh = idx & 31, i = idx >> 5;
        int kh = vh >> 1, j = vh & 1;
        long row = ((long)b * 4096 + c * 64 + i) * 8320 + 8192 + kh * 4;
        float bb = (float)mixedH[row + j];
        float aa = (float)mixedH[row + 2 + j];
        beta[((long)b * 4096 + c * 64 + i) * 32 + vh] = 1.f / (1.f + expf(-bb));
        float x = aa + dt_bias[vh];
        float sp = (x > 15.f) ? x : log1pf(expf(x));
        gs[vh][i] = -expf(A_log[vh]) * sp;
    }
    __syncthreads();
    if (threadIdx.x < 32) {
        int vh = threadIdx.x;
        float cum = 0.f;
        float* gout = gcum + ((long)(b * 32 + vh)) * 4096 + c * 64;
        for (int i = 0; i < 64; ++i) { cum += gs[vh][i]; gout[i] = cum; }
    }
}

// ---------------------------------------------------------------------------
// l2norm rows of 128 (in-place, f16). q rows get extra 1/sqrt(128).
// grid: 65536 blocks * 4 waves; rows 0..131071 = q, 131072..262143 = k.
// ---------------------------------------------------------------------------
__global__ __launch_bounds__(256) void l2norm_k(half_t* __restrict__ qb,
                                                half_t* __restrict__ kb) {
    int w = threadIdx.x >> 6, lane = threadIdx.x & 63;
    long rid = (long)blockIdx.x * 4 + w;
    half_t* base;
    float sc;
    if (rid < 131072) { base = qb + rid * 128; sc = 0.08838834764831845f; }
    else              { base = kb + (rid - 131072) * 128; sc = 1.f; }
    half2_t hv = *(half2_t*)(base + lane * 2);
    float f0 = (float)hv[0], f1 = (float)hv[1];
    float ss = f0 * f0 + f1 * f1;
#pragma unroll
    for (int off = 32; off; off >>= 1) ss += __shfl_xor(ss, off);
    float r = rsqrtf(ss + 1e-6f) * sc;
    half2_t o; o[0] = (half_t)(f0 * r); o[1] = (half_t)(f1 * r);
    *(half2_t*)(base + lane * 2) = o;
}

// ---------------------------------------------------------------------------
// Phase 1: per (b,vh,chunk): A, T=(I-A)^-1, attn, v_t, -kc.  grid 4096.
// ---------------------------------------------------------------------------
__global__ __launch_bounds__(256) void phase1_k(const half_t* __restrict__ qb,
                                                const half_t* __restrict__ kb,
                                                const half_t* __restrict__ vb,
                                                const float* __restrict__ beta,
                                                const float* __restrict__ gcum,
                                                half_t* __restrict__ attnW,
                                                half_t* __restrict__ vtW,
                                                half_t* __restrict__ kcW) {
    __shared__ float AT[64 * 64];       // swizzled rows (256 B); A then T in-place
    __shared__ half_t XT[256 * 64];     // rows 0..127 = (v*beta)^T, 128..255 = (k*beta*e^g)^T
    __shared__ float gcS[64], betaS[64], egS[64];
    int blk = blockIdx.x;
    int c = blk & 63, vh = (blk >> 6) & 31, b = blk >> 11;
    int kh = vh >> 1;
    int tid = threadIdx.x, lane = tid & 63, w = tid >> 6, lo = lane & 15, hi = lane >> 4;
    long rowbase = (long)b * 4096 + c * 64;
    if (tid < 64) {
        float g = gcum[((long)(b * 32 + vh)) * 4096 + c * 64 + tid];
        gcS[tid] = g; egS[tid] = expf(g);
        betaS[tid] = beta[(rowbase + tid) * 32 + vh];
    }
    // G = kn@kn^T, attn_raw = qn@kn^T via global-gather fragments
    const half_t* kR = kb + rowbase * 2048 + kh * 128;
    const half_t* qR = qb + rowbase * 2048 + kh * 128;
    f32x4 accG[4] = {}, accA[4] = {};
#pragma unroll
    for (int kt = 0; kt < 4; ++kt) {
        half8 ak = *(const half8*)(kR + (long)(w * 16 + lo) * 2048 + kt * 32 + hi * 8);
        half8 aq = *(const half8*)(qR + (long)(w * 16 + lo) * 2048 + kt * 32 + hi * 8);
#pragma unroll
        for (int n = 0; n < 4; ++n) {
            half8 bk = *(const half8*)(kR + (long)(n * 16 + lo) * 2048 + kt * 32 + hi * 8);
            accG[n] = MFMA16(ak, bk, accG[n]);
            accA[n] = MFMA16(aq, bk, accA[n]);
        }
    }
    __syncthreads();  // gcS/betaS ready
    half_t* attnB = attnW + (long)blk * 4096;
#pragma unroll
    for (int n = 0; n < 4; ++n)
#pragma unroll
        for (int e = 0; e < 4; ++e) {
            int i = w * 16 + hi * 4 + e;
            int j = n * 16 + lo;
            float dec = (j < i) ? expf(gcS[i] - gcS[j]) : 0.f;
            float av = (j < i) ? (-betaS[i] * accG[n][e] * dec) : (j == i ? 1.f : 0.f);
            at_wr(AT, i, j, av);
            attnB[(long)i * 64 + j] = (half_t)((j < i) ? accA[n][e] * dec : 0.f);
        }
    __syncthreads();
    if (w == 0) {
        // forward substitution, in place: T[i][j] = d_ij + sum_{p<i} A[i][p]*T[p][j]
        int j = lane;
        for (int i = 1; i < 64; ++i) {
            float acc2 = 0.f;
            for (int p = 0; p < i; ++p) acc2 += at_rd(AT, i, p) * at_rd(AT, p, j);
            at_wr(AT, i, j, (j == i) ? 1.f : acc2);
        }
    } else {
        // build XT (transposed operands), overlapped with the solve
        for (int idx = tid - 64; idx < 4096; idx += 192) {
            int p = idx >> 6, dp = idx & 63;
            float bb = betaS[p], be = betaS[p] * egS[p];
            half2_t vv = *(const half2_t*)(vb + (rowbase + p) * 4096 + vh * 128 + dp * 2);
            half2_t kk = *(const half2_t*)(kb + (rowbase + p) * 2048 + kh * 128 + dp * 2);
            w64(XT, dp * 2,       p, (float)vv[0] * bb);
            w64(XT, dp * 2 + 1,   p, (float)vv[1] * bb);
            w64(XT, 128 + dp * 2,     p, (float)kk[0] * be);
            w64(XT, 128 + dp * 2 + 1, p, (float)kk[1] * be);
        }
    }
    __syncthreads();
    // [v_t | kc] = T @ [v*beta | k*beta*e^g]  (wave w -> output cols 64w..64w+63)
    f32x4 accO[4][4] = {};
#pragma unroll
    for (int kt = 0; kt < 2; ++kt) {
        half8 tf[4];
#pragma unroll
        for (int m = 0; m < 4; ++m) {
            int r = m * 16 + lo;
            int b0 = (kt * 32 + hi * 8) * 4;
            f32x4 x0 = *(const f32x4*)((const char*)AT + r * 256 + (b0 ^ ((r & 7) << 4)));
            f32x4 x1 = *(const f32x4*)((const char*)AT + r * 256 + ((b0 + 16) ^ ((r & 7) << 4)));
            half8 h;
            h[0] = (half_t)x0[0]; h[1] = (half_t)x0[1]; h[2] = (half_t)x0[2]; h[3] = (half_t)x0[3];
            h[4] = (half_t)x1[0]; h[5] = (half_t)x1[1]; h[6] = (half_t)x1[2]; h[7] = (half_t)x1[3];
            tf[m] = h;
        }
#pragma unroll
        for (int n = 0; n < 4; ++n) {
            half8 bx = frag64(XT, w * 64 + n * 16 + lo, kt * 32 + hi * 8);
#pragma unroll
            for (int m = 0; m < 4; ++m) accO[m][n] = MFMA16(tf[m], bx, accO[m][n]);
        }
    }
    long ob = (long)blk * 8192;
#pragma unroll
    for (int m = 0; m < 4; ++m)
#pragma unroll
        for (int n = 0; n < 4; ++n)
#pragma unroll
            for (int e = 0; e < 4; ++e) {
                int i = m * 16 + hi * 4 + e;
                int dc = w * 64 + n * 16 + lo;
                float v = accO[m][n][e];
                if (dc < 128) vtW[ob + (long)i * 128 + dc] = (half_t)v;
                else          kcW[ob + (long)i * 128 + dc - 128] = (half_t)(-v);  // store -kc
            }
}

// ---------------------------------------------------------------------------
// Phase 2 (R2): sequential chunk scan per (b,vh,DV-slice of 32). grid 256
// (js in high bits so the 4 slices of one bvh share an XCD/L2). State^T
// slice (32x128 f16) in LDS; register double-buffered operand prefetch.
// ---------------------------------------------------------------------------
struct P2Ops {
    half8 kcf[4], qf[4], k8[4];
    half8 atf[2];
    half_t vtv[8];
    float gm, gi, g63;
};

__global__ __launch_bounds__(256, 1) void phase2_k(const half_t* __restrict__ qb,
                                                   const half_t* __restrict__ kb,
                                                   const float* __restrict__ gcum,
                                                   const half_t* __restrict__ attnW,
                                                   const half_t* __restrict__ vtW,
                                                   const half_t* __restrict__ kcW,
                                                   half_t* __restrict__ coreH) {
    __shared__ half_t SHs[32 * 128];  // S^T slice rows j (256 B, swizzled)
    __shared__ half_t vnT[32 * 64];   // v_new^T rows j (128 B, swizzled)
    __shared__ half_t kdT[128 * 64];  // kd rows d (128 B, swizzled)
    int blk = blockIdx.x;
    int bvh = blk & 63, js = blk >> 6;   // js slowest -> same XCD per bvh
    int vh = bvh & 31, b = bvh >> 5, kh = vh >> 1;
    int j0 = js * 32;
    int tid = threadIdx.x, lane = tid & 63, w = tid >> 6, lo = lane & 15, hi = lane >> 4;
    int ii = tid >> 2, dseg = tid & 3;   // kdT-build ownership
    int jm = w >> 1, dql = (w & 1) * 4;  // update-tile ownership
    for (int idx = tid; idx < 32 * 128; idx += 256) SHs[idx] = (half_t)0.f;
    __syncthreads();
    const float* gbase = gcum + (long)bvh * 4096;

    auto loadops = [&](int c, P2Ops& o) {
        long pb = (long)bvh * 64 + c;
        const half_t* kcG = kcW + pb * 8192;   // holds -kc
        const half_t* vtG = vtW + pb * 8192;
        const half_t* atG = attnW + pb * 4096;
        long rowbase = (long)b * 4096 + c * 64;
        const float* gp = gbase + c * 64;
#pragma unroll
        for (int kt = 0; kt < 4; ++kt) {
            o.kcf[kt] = *(const half8*)(kcG + (long)(w * 16 + lo) * 128 + kt * 32 + hi * 8);
            o.qf[kt] = *(const half8*)(qb + (rowbase + w * 16 + lo) * 2048 + kh * 128 +
                                       kt * 32 + hi * 8);
        }
#pragma unroll
        for (int kt2 = 0; kt2 < 2; ++kt2)
            o.atf[kt2] = *(const half8*)(atG + (long)(w * 16 + lo) * 64 + kt2 * 32 + hi * 8);
#pragma unroll
        for (int s = 0; s < 4; ++s)
            o.k8[s] = *(const half8*)(kb + (rowbase + ii) * 2048 + kh * 128 + dseg * 32 + s * 8);
#pragma unroll
        for (int n = 0; n < 2; ++n)
#pragma unroll
            for (int e = 0; e < 4; ++e)
                o.vtv[n * 4 + e] = vtG[(long)(w * 16 + hi * 4 + e) * 128 + j0 + n * 16 + lo];
        o.gm = gp[w * 16 + lo];
        o.gi = gp[ii];
        o.g63 = gp[63];
    };

    auto step = [&](int c, P2Ops& o, P2Ops& nx) {
        long rowbase = (long)b * 4096 + c * 64;
        loadops(c + 1 < 64 ? c + 1 : 63, nx);  // prefetch (hidden under MFMAs)
        // ---- S-slice fragments (reused for kc@S and q@S) ----
        half8 bS[4][2];
#pragma unroll
        for (int kt = 0; kt < 4; ++kt) {
            bS[kt][0] = frag128(SHs, lo, kt * 32 + hi * 8);
            bS[kt][1] = frag128(SHs, 16 + lo, kt * 32 + hi * 8);
        }
        // ---- v_new = v_t + (-kc)@S  (wave w owns i-tile w; n = j tiles) ----
        f32x4 accV[2];
#pragma unroll
        for (int n = 0; n < 2; ++n)
#pragma unroll
            for (int e = 0; e < 4; ++e) accV[n][e] = (float)o.vtv[n * 4 + e];
#pragma unroll
        for (int kt = 0; kt < 4; ++kt) {
            accV[0] = MFMA16(o.kcf[kt], bS[kt][0], accV[0]);
            accV[1] = MFMA16(o.kcf[kt], bS[kt][1], accV[1]);
        }
        // write v_new^T to LDS (C layout: col j = n*16+lo, rows i0..i0+3 contig)
#pragma unroll
        for (int n = 0; n < 2; ++n) {
            int j = n * 16 + lo, i0 = w * 16 + hi * 4;
            half4_t h4;
            h4[0] = (half_t)accV[n][0]; h4[1] = (half_t)accV[n][1];
            h4[2] = (half_t)accV[n][2]; h4[3] = (half_t)accV[n][3];
            *(half4_t*)((char*)vnT + j * 128 + ((i0 * 2) ^ ((j & 7) << 4))) = h4;
        }
        // build kdT[d][i] = k[i][d]*exp(g63-g_i) (thread owns i=ii, d-seg dseg)
        {
            float ek = expf(o.g63 - o.gi);
#pragma unroll
            for (int s = 0; s < 4; ++s)
#pragma unroll
                for (int e2 = 0; e2 < 8; ++e2)
                    w64(kdT, dseg * 32 + s * 8 + e2, ii, (float)o.k8[s][e2] * ek);
        }
        __syncthreads();  // S1: vnT, kdT ready
        // ---- out = (q*e^g)@S + attn@v_new ----
        float egm = expf(o.gm);
        f32x4 accO[2] = {};
#pragma unroll
        for (int kt = 0; kt < 4; ++kt) {
            half8 aq;
#pragma unroll
            for (int e2 = 0; e2 < 8; ++e2) aq[e2] = (half_t)((float)o.qf[kt][e2] * egm);
            accO[0] = MFMA16(aq, bS[kt][0], accO[0]);
            accO[1] = MFMA16(aq, bS[kt][1], accO[1]);
        }
#pragma unroll
        for (int kt2 = 0; kt2 < 2; ++kt2) {
            half8 bV0 = frag64(vnT, lo, kt2 * 32 + hi * 8);
            half8 bV1 = frag64(vnT, 16 + lo, kt2 * 32 + hi * 8);
            accO[0] = MFMA16(o.atf[kt2], bV0, accO[0]);
            accO[1] = MFMA16(o.atf[kt2], bV1, accO[1]);
        }
        // ---- update MFMAs: S^T_new -= ... (reads vnT/kdT only; RMW after S2)
        f32x4 accU[4] = {};
#pragma unroll
        for (int kt2 = 0; kt2 < 2; ++kt2) {
            half8 avn = frag64(vnT, jm * 16 + lo, kt2 * 32 + hi * 8);
#pragma unroll
            for (int dnn = 0; dnn < 4; ++dnn) {
                half8 bkd = frag64(kdT, (dql + dnn) * 16 + lo, kt2 * 32 + hi * 8);
                accU[dnn] = MFMA16(avn, bkd, accU[dnn]);
            }
        }
        // out store (no LDS dependence)
#pragma unroll
        for (int n = 0; n < 2; ++n)
#pragma unroll
            for (int e = 0; e < 4; ++e)
                coreH[(rowbase + w * 16 + hi * 4 + e) * 4096 + vh * 128 + j0 + n * 16 + lo] =
                    (half_t)accO[n][e];
        __syncthreads();  // S2: all q@S reads of SHs done
        float egl = expf(o.g63);
#pragma unroll
        for (int dnn = 0; dnn < 4; ++dnn)
#pragma unroll
            for (int e = 0; e < 4; ++e) {
                int j = jm * 16 + hi * 4 + e;
                int d = (dql + dnn) * 16 + lo;
                char* p = (char*)SHs + j * 256 + ((d * 2) ^ ((j & 7) << 4));
                float old = (float)*(half_t*)p;
                *(half_t*)p = (half_t)(old * egl + accU[dnn][e]);
            }
        __syncthreads();  // S3: state updated for next chunk
    };

    P2Ops opsA, opsB;
    loadops(0, opsA);
    for (int c = 0; c < 64; c += 2) {
        step(c, opsA, opsB);
        step(c + 1, opsB, opsA);
    }
}

// ---------------------------------------------------------------------------
// Gated RMSNorm + silu(z) gate, IN-PLACE on coreH. One wave per (b,s,vh) row.
// grid: 65536 (= B*S*HV/4 waves).
// ---------------------------------------------------------------------------
__global__ __launch_bounds__(256) void normgate_k(half_t* __restrict__ coreH,
                                                  const half_t* __restrict__ zH,
                                                  const float* __restrict__ norm_w) {
    int w = threadIdx.x >> 6, lane = threadIdx.x & 63;
    long rid = (long)blockIdx.x * 4 + w;  // < 262144
    long bs = rid >> 5;
    int vh = rid & 31;
    half_t* cr = coreH + bs * 4096 + vh * 128;
    half2_t cv = *(half2_t*)(cr + lane * 2);
    float f0 = (float)cv[0], f1 = (float)cv[1];
    float ss = f0 * f0 + f1 * f1;
#pragma unroll
    for (int off = 32; off; off >>= 1) ss += __shfl_xor(ss, off);
    float rs = rsqrtf(ss * (1.f / 128.f) + 1e-6f);
    half2_t zz = *(const half2_t*)(zH + bs * 4096 + vh * 128 + lane * 2);
    float z0 = (float)zz[0], z1 = (float)zz[1];
    float s0 = z0 / (1.f + expf(-z0)), s1 = z1 / (1.f + expf(-z1));
    float w0 = norm_w[lane * 2], w1 = norm_w[lane * 2 + 1];
    half2_t o;
    o[0] = (half_t)(f0 * rs * w0 * s0);
    o[1] = (half_t)(f1 * rs * w1 * s1);
    *(half2_t*)(cr + lane * 2) = o;
}

// ---------------------------------------------------------------------------
// Host launcher.  Workspace layout (MiB offsets), hand-aliased, peak 370 MiB:
//   [0,32)    qb          (conv..phase2)   | overlay: hiddenH (cast..gemm1)
//   [32,64)   kb          (conv..phase2)   | overlay: W1T head
//   [64,128)  vb          (conv..phase1)   | overlay: W1T tail [64,81);
//                                            later coreH (phase2..gemm2)
//   [128,129) betaB   [129,130) gcum
//   [130,146) WoT         (build..gemm2)
//   [146,210) zH          (gemm1b..normgate)
//   [210,340) mixedH      (gemm1a..gate)   | overlay after: attnW [210,242),
//   [340,370)                                vtW [242,306), kcW [306,370)
// ---------------------------------------------------------------------------
extern "C" void kernel_launch(void* const* d_in, const int* in_sizes, int n_in,
                              void* d_out, int out_size, void* d_ws, size_t ws_size,
                              hipStream_t stream) {
    const float* hidden  = (const float*)d_in[0];
    const float* W_qkvz  = (const float*)d_in[1];
    const float* W_ba    = (const float*)d_in[2];
    const float* conv_w  = (const float*)d_in[3];
    const float* A_log   = (const float*)d_in[4];
    const float* dt_bias = (const float*)d_in[5];
    const float* norm_w  = (const float*)d_in[6];
    const float* W_out   = (const float*)d_in[7];
    float* out = (float*)d_out;

    char* ws = (char*)d_ws;
    const size_t MB = 1ull << 20;
    half_t* qb      = (half_t*)(ws + 0);
    half_t* kb      = (half_t*)(ws + 32 * MB);
    half_t* vb      = (half_t*)(ws + 64 * MB);
    float*  betaB   = (float*) (ws + 128 * MB);
    float*  gcum    = (float*) (ws + 129 * MB);
    half_t* WoT     = (half_t*)(ws + 130 * MB);
    half_t* zH      = (half_t*)(ws + 146 * MB);
    half_t* mixedH  = (half_t*)(ws + 210 * MB);
    half_t* attnW   = (half_t*)(ws + 210 * MB);  // overlays dead mixedH
    half_t* vtW     = (half_t*)(ws + 242 * MB);
    half_t* kcW     = (half_t*)(ws + 306 * MB);
    half_t* hiddenH = (half_t*)(ws + 0);         // overlays not-yet-written qb
    half_t* W1T     = (half_t*)(ws + 32 * MB);   // overlays kb + head of vb
    half_t* coreH   = (half_t*)(ws + 64 * MB);   // overlays dead vb
    (void)ws_size; (void)in_sizes; (void)n_in; (void)out_size;

    // 1. casts / transposes
    cast_h_k<<<16384, 256, 0, stream>>>(hidden, hiddenH);
    build_w1t_k<<<dim3(388, 64), 256, 0, stream>>>(W_qkvz, W_ba, W1T);
    build_wot_k<<<dim3(64, 128), 256, 0, stream>>>(W_out, WoT);
    // 2. fused projection, split: qkv+ba (N=8320) then z (N=4096); K=2048
    gemm_k<1><<<dim3(64, 65), 256, 0, stream>>>(hiddenH, W1T, mixedH, 2048, 8320);
    gemm_k<1><<<dim3(64, 32), 256, 0, stream>>>(hiddenH, W1T + (size_t)8320 * 2048, zH,
                                                2048, 4096);
    // 3. conv + silu ; gates ; l2norm
    conv_silu_k<<<dim3(32, 64), 256, 0, stream>>>(mixedH, conv_w, qb, kb, vb);
    gate_beta_k<<<128, 256, 0, stream>>>(mixedH, A_log, dt_bias, betaB, gcum);
    l2norm_k<<<65536, 256, 0, stream>>>(qb, kb);
    // 4. delta-rule core
    phase1_k<<<4096, 256, 0, stream>>>(qb, kb, vb, betaB, gcum, attnW, vtW, kcW);
    phase2_k<<<256, 256, 0, stream>>>(qb, kb, gcum, attnW, vtW, kcW, coreH);
    // 5. gated RMSNorm (in-place) + output projection (M=8192, N=2048, K=4096)
    normgate_k<<<65536, 256, 0, stream>>>(coreH, zH, norm_w);
    gemm_k<0><<<dim3(64, 16), 256, 0, stream>>>(coreH, WoT, out, 4096, 2048);
}

// Round 4
// 1384.254 us; speedup vs baseline: 1.7823x; 1.1445x over previous
//
#include <hip/hip_runtime.h>
#include <cstdint>
#include <cstddef>

// ---------------------------------------------------------------------------
// Qwen3.5 GatedDeltaNet forward, MI355X (gfx950), f16-MFMA implementation.
// B=2, S=4096, H=2048, HK=16, HV=32, DK=DV=128, KW=4, CS=64.
// Workspace peak: 370 MiB (hand-aliased layout, see kernel_launch).
// R2: phase2 split 4x across DV (grid 64 -> 256), reg-prefetch, 3 barriers.
// R3: phase1 forward-substitution made register-resident + fully unrolled
//     (was a 2016-step LDS-round-trip latency chain); T stored f16 into the
//     dead A buffer and consumed directly as MFMA fragments.
// ---------------------------------------------------------------------------

typedef _Float16 half_t;
typedef _Float16 half2_t __attribute__((ext_vector_type(2)));
typedef _Float16 half4_t __attribute__((ext_vector_type(4)));
typedef _Float16 half8   __attribute__((ext_vector_type(8)));
typedef float    f32x4   __attribute__((ext_vector_type(4)));

#define MFMA16(a, b, c) __builtin_amdgcn_mfma_f32_16x16x32_f16((a), (b), (c), 0, 0, 0)

#define AS1 __attribute__((address_space(1)))
#define AS3 __attribute__((address_space(3)))

// async global->LDS, 16B per lane; LDS dest is wave-uniform base + lane*16.
__device__ __forceinline__ void gload16(void* lds, const void* g) {
    __builtin_amdgcn_global_load_lds((AS1 void*)(g), (AS3 void*)(lds), 16, 0, 0);
}

// ---- swizzled-LDS access helpers (XOR byte-bits 4..6 with row&7) ----------
// f32 array, rows of 64 floats (256 B). Used for A (solve input).
__device__ __forceinline__ void at_wr(float* AT, int i, int j, float v) {
    *(float*)((char*)AT + i * 256 + ((j * 4) ^ ((i & 7) << 4))) = v;
}
// f16 array, rows of 64 halfs (128 B): XT, vnT, kdT, T-as-f16.
__device__ __forceinline__ half8 frag64(const half_t* base, int row, int koff) {
    return *(const half8*)((const char*)base + row * 128 + ((koff * 2) ^ ((row & 7) << 4)));
}
__device__ __forceinline__ void w64(half_t* base, int row, int col, float v) {
    *(half_t*)((char*)base + row * 128 + ((col * 2) ^ ((row & 7) << 4))) = (half_t)v;
}
// f16 array, rows of 128 halfs (256 B): SHs (state^T slice).
__device__ __forceinline__ half8 frag128(const half_t* base, int row, int koff) {
    return *(const half8*)((const char*)base + row * 256 + ((koff * 2) ^ ((row & 7) << 4)));
}

// ---------------------------------------------------------------------------
// Cast / transpose prep kernels
// ---------------------------------------------------------------------------
__global__ __launch_bounds__(256) void cast_h_k(const float* __restrict__ src,
                                                half_t* __restrict__ dst) {
    long i = (long)blockIdx.x * 256 + threadIdx.x;  // processes 4 elems
    f32x4 v = *(const f32x4*)(src + i * 4);
    half4_t h;
    h[0] = (half_t)v[0]; h[1] = (half_t)v[1]; h[2] = (half_t)v[2]; h[3] = (half_t)v[3];
    *(half4_t*)(dst + i * 4) = h;
}

// Column-permuted W1T[n][k]:
//   n in [0,2048)     : q flat   (kh=n>>7, d=n&127)       -> Wq col kh*768+d
//   n in [2048,4096)  : k flat                             -> Wq col kh*768+128+d
//   n in [4096,8192)  : v flat   (vh=(n-4096)>>7)          -> Wq col kh*768+256+jj*128+d
//   n in [8192,8256)  : ba                                 -> Wba col n-8192
//   n in [8256,8320)  : zero pad
//   n in [8320,12416) : z flat   (vh=(n-8320)>>7)          -> Wq col kh*768+512+jj*128+d
__global__ __launch_bounds__(256) void build_w1t_k(const float* __restrict__ Wq,
                                                   const float* __restrict__ Wba,
                                                   half_t* __restrict__ W1T) {
    __shared__ half_t tile[32][33];
    int n0 = blockIdx.x * 32, k0 = blockIdx.y * 32;
    int tx = threadIdx.x & 31, ty = threadIdx.x >> 5;
#pragma unroll
    for (int t = 0; t < 4; ++t) {
        int k = k0 + ty + t * 8, n = n0 + tx;
        float v = 0.f;
        if (n < 2048) {
            int kh = n >> 7, d = n & 127;
            v = Wq[(long)k * 12288 + kh * 768 + d];
        } else if (n < 4096) {
            int n2 = n - 2048; int kh = n2 >> 7, d = n2 & 127;
            v = Wq[(long)k * 12288 + kh * 768 + 128 + d];
        } else if (n < 8192) {
            int n3 = n - 4096; int vh = n3 >> 7, d = n3 & 127;
            int kh = vh >> 1, jj = vh & 1;
            v = Wq[(long)k * 12288 + kh * 768 + 256 + jj * 128 + d];
        } else if (n < 8256) {
            v = Wba[(long)k * 64 + (n - 8192)];
        } else if (n >= 8320) {
            int n4 = n - 8320; int vh = n4 >> 7, d = n4 & 127;
            int kh = vh >> 1, jj = vh & 1;
            v = Wq[(long)k * 12288 + kh * 768 + 512 + jj * 128 + d];
        }
        tile[ty + t * 8][tx] = (half_t)v;
    }
    __syncthreads();
#pragma unroll
    for (int t = 0; t < 4; ++t) {
        int n = n0 + ty + t * 8, k = k0 + tx;
        W1T[(long)n * 2048 + k] = tile[tx][ty + t * 8];
    }
}

// WoT[n][k] = W_out[k][n]; n < 2048, k < 4096
__global__ __launch_bounds__(256) void build_wot_k(const float* __restrict__ Wo,
                                                   half_t* __restrict__ WoT) {
    __shared__ half_t tile[32][33];
    int n0 = blockIdx.x * 32, k0 = blockIdx.y * 32;
    int tx = threadIdx.x & 31, ty = threadIdx.x >> 5;
#pragma unroll
    for (int t = 0; t < 4; ++t) {
        int k = k0 + ty + t * 8, n = n0 + tx;
        tile[ty + t * 8][tx] = (half_t)Wo[(long)k * 2048 + n];
    }
    __syncthreads();
#pragma unroll
    for (int t = 0; t < 4; ++t) {
        int n = n0 + ty + t * 8, k = k0 + tx;
        WoT[(long)n * 4096 + k] = tile[tx][ty + t * 8];
    }
}

// ---------------------------------------------------------------------------
// m97-style 128x128 f16 GEMM: C = A(MxK) * Bt(NxK)^T.  grid (M/128, N/128).
// ---------------------------------------------------------------------------
template <int OUT_F16>
__global__ __launch_bounds__(256) void gemm_k(const half_t* __restrict__ A,
                                              const half_t* __restrict__ Bt,
                                              void* __restrict__ C, int K, int ldc) {
    __shared__ half_t As[128 * 32];
    __shared__ half_t Bs[128 * 32];
    const int tid = threadIdx.x, lane = tid & 63, w = tid >> 6;
    const int lo = lane & 15, hi = lane >> 4;
    const int wr = w >> 1, wc = w & 1;
    const long tm = blockIdx.x, tn = blockIdx.y;
    const half_t* Ab = A + tm * 128 * (long)K;
    const half_t* Bb = Bt + tn * 128 * (long)K;
    f32x4 acc[4][4] = {};
    const int rl = (lane >> 2);       // 0..15 row-within-16
    const int kl = (lane & 3) * 8;    // 0/8/16/24
    for (int k0 = 0; k0 < K; k0 += 32) {
#pragma unroll
        for (int t = 0; t < 2; ++t) {
            int seg = w * 2 + t;      // 0..7, 16 rows each
            int r = seg * 16 + rl;
            gload16(As + seg * 512, Ab + (long)r * K + k0 + kl);
            gload16(Bs + seg * 512, Bb + (long)r * K + k0 + kl);
        }
        __syncthreads();  // compiler drains vmcnt before s_barrier
        half8 af[4], bf[4];
#pragma unroll
        for (int m = 0; m < 4; ++m)
            af[m] = *(const half8*)(As + (wr * 64 + m * 16 + lo) * 32 + hi * 8);
#pragma unroll
        for (int n = 0; n < 4; ++n)
            bf[n] = *(const half8*)(Bs + (wc * 64 + n * 16 + lo) * 32 + hi * 8);
#pragma unroll
        for (int m = 0; m < 4; ++m)
#pragma unroll
            for (int n = 0; n < 4; ++n) acc[m][n] = MFMA16(af[m], bf[n], acc[m][n]);
        __syncthreads();
    }
#pragma unroll
    for (int m = 0; m < 4; ++m)
#pragma unroll
        for (int n = 0; n < 4; ++n)
#pragma unroll
            for (int e = 0; e < 4; ++e) {
                long row = tm * 128 + wr * 64 + m * 16 + hi * 4 + e;
                long col = tn * 128 + wc * 64 + n * 16 + lo;
                if (OUT_F16)
                    ((half_t*)C)[row * ldc + col] = (half_t)acc[m][n][e];
                else
                    ((float*)C)[row * ldc + col] = acc[m][n][e];
            }
}

// ---------------------------------------------------------------------------
// Causal depthwise conv (KW=4) + SiLU over mixed (B,S,8320) channels 0..8191.
// grid: (32 channel-blocks, B*32 s-chunks of 128)
// ---------------------------------------------------------------------------
__global__ __launch_bounds__(256) void conv_silu_k(const half_t* __restrict__ mixedH,
                                                   const float* __restrict__ conv_w,
                                                   half_t* __restrict__ qb,
                                                   half_t* __restrict__ kb,
                                                   half_t* __restrict__ vb) {
    int ch = blockIdx.x * 256 + threadIdx.x;     // 0..8191 (== conv channel)
    int b = blockIdx.y >> 5, sc = blockIdx.y & 31;
    int s0 = sc * 128;
    half_t* dptr;
    long dstr;
    if (ch < 2048)      { dptr = qb + ch;          dstr = 2048; }
    else if (ch < 4096) { dptr = kb + (ch - 2048); dstr = 2048; }
    else                { dptr = vb + (ch - 4096); dstr = 4096; }
    float w0 = conv_w[ch * 4 + 0], w1 = conv_w[ch * 4 + 1];
    float w2 = conv_w[ch * 4 + 2], w3 = conv_w[ch * 4 + 3];
    const half_t* src = mixedH + (long)b * 4096 * 8320 + ch;
    float x0 = (s0 >= 3) ? (float)src[(long)(s0 - 3) * 8320] : 0.f;
    float x1 = (s0 >= 2) ? (float)src[(long)(s0 - 2) * 8320] : 0.f;
    float x2 = (s0 >= 1) ? (float)src[(long)(s0 - 1) * 8320] : 0.f;
    for (int s = s0; s < s0 + 128; ++s) {
        float x3 = (float)src[(long)s * 8320];
        float y = w0 * x0 + w1 * x1 + w2 * x2 + w3 * x3;
        y = y / (1.f + expf(-y));  // silu
        dptr[((long)b * 4096 + s) * dstr] = (half_t)y;
        x0 = x1; x1 = x2; x2 = x3;
    }
}

// ---------------------------------------------------------------------------
// beta = sigmoid(b), g = -exp(A_log)*softplus(a+dt_bias), per-chunk cumsum.
// grid: B*64 blocks (one per (b, chunk)); ba at mixedH cols 8192..8255.
// ---------------------------------------------------------------------------
__global__ __launch_bounds__(256) void gate_beta_k(const half_t* __restrict__ mixedH,
                                                   const float* __restrict__ A_log,
                                                   const float* __restrict__ dt_bias,
                                                   float* __restrict__ beta,
                                                   float* __restrict__ gcum) {
    __shared__ float gs[32][64];
    int b = blockIdx.x >> 6, c = blockIdx.x & 63;
    for (int idx = threadIdx.x; idx < 2048; idx += 256) {
        int vh = idx & 31, i = idx >> 5;
        int kh = vh >> 1, j = vh & 1;
        long row = ((long)b * 4096 + c * 64 + i) * 8320 + 8192 + kh * 4;
        float bb = (float)mixedH[row + j];
        float aa = (float)mixedH[row + 2 + j];
        beta[((long)b * 4096 + c * 64 + i) * 32 + vh] = 1.f / (1.f + expf(-bb));
        float x = aa + dt_bias[vh];
        float sp = (x > 15.f) ? x : log1pf(expf(x));
        gs[vh][i] = -expf(A_log[vh]) * sp;
    }
    __syncthreads();
    if (threadIdx.x < 32) {
        int vh = threadIdx.x;
        float cum = 0.f;
        float* gout = gcum + ((long)(b * 32 + vh)) * 4096 + c * 64;
        for (int i = 0; i < 64; ++i) { cum += gs[vh][i]; gout[i] = cum; }
    }
}

// ---------------------------------------------------------------------------
// l2norm rows of 128 (in-place, f16). q rows get extra 1/sqrt(128).
// grid: 65536 blocks * 4 waves; rows 0..131071 = q, 131072..262143 = k.
// ---------------------------------------------------------------------------
__global__ __launch_bounds__(256) void l2norm_k(half_t* __restrict__ qb,
                                                half_t* __restrict__ kb) {
    int w = threadIdx.x >> 6, lane = threadIdx.x & 63;
    long rid = (long)blockIdx.x * 4 + w;
    half_t* base;
    float sc;
    if (rid < 131072) { base = qb + rid * 128; sc = 0.08838834764831845f; }
    else              { base = kb + (rid - 131072) * 128; sc = 1.f; }
    half2_t hv = *(half2_t*)(base + lane * 2);
    float f0 = (float)hv[0], f1 = (float)hv[1];
    float ss = f0 * f0 + f1 * f1;
#pragma unroll
    for (int off = 32; off; off >>= 1) ss += __shfl_xor(ss, off);
    float r = rsqrtf(ss + 1e-6f) * sc;
    half2_t o; o[0] = (half_t)(f0 * r); o[1] = (half_t)(f1 * r);
    *(half2_t*)(base + lane * 2) = o;
}

// ---------------------------------------------------------------------------
// Phase 1: per (b,vh,chunk): A, T=(I-A)^-1, attn, v_t, -kc.  grid 4096.
// R3: solve is register-resident in wave 0 (fully unrolled, 4-way split
// accumulators, uniform-broadcast f32x4 reads of A rows); T written back
// as f16 into the dead A buffer and read directly as MFMA A-fragments.
// ---------------------------------------------------------------------------
__global__ __launch_bounds__(256) void phase1_k(const half_t* __restrict__ qb,
                                                const half_t* __restrict__ kb,
                                                const half_t* __restrict__ vb,
                                                const float* __restrict__ beta,
                                                const float* __restrict__ gcum,
                                                half_t* __restrict__ attnW,
                                                half_t* __restrict__ vtW,
                                                half_t* __restrict__ kcW) {
    __shared__ float AT[64 * 64];       // swizzled rows (256 B); A f32, then T f16
    __shared__ half_t XT[256 * 64];     // rows 0..127 = (v*beta)^T, 128..255 = (k*beta*e^g)^T
    __shared__ float gcS[64], betaS[64], egS[64];
    int blk = blockIdx.x;
    int c = blk & 63, vh = (blk >> 6) & 31, b = blk >> 11;
    int kh = vh >> 1;
    int tid = threadIdx.x, lane = tid & 63, w = tid >> 6, lo = lane & 15, hi = lane >> 4;
    long rowbase = (long)b * 4096 + c * 64;
    if (tid < 64) {
        float g = gcum[((long)(b * 32 + vh)) * 4096 + c * 64 + tid];
        gcS[tid] = g; egS[tid] = expf(g);
        betaS[tid] = beta[(rowbase + tid) * 32 + vh];
    }
    // G = kn@kn^T, attn_raw = qn@kn^T via global-gather fragments
    const half_t* kR = kb + rowbase * 2048 + kh * 128;
    const half_t* qR = qb + rowbase * 2048 + kh * 128;
    f32x4 accG[4] = {}, accA[4] = {};
#pragma unroll
    for (int kt = 0; kt < 4; ++kt) {
        half8 ak = *(const half8*)(kR + (long)(w * 16 + lo) * 2048 + kt * 32 + hi * 8);
        half8 aq = *(const half8*)(qR + (long)(w * 16 + lo) * 2048 + kt * 32 + hi * 8);
#pragma unroll
        for (int n = 0; n < 4; ++n) {
            half8 bk = *(const half8*)(kR + (long)(n * 16 + lo) * 2048 + kt * 32 + hi * 8);
            accG[n] = MFMA16(ak, bk, accG[n]);
            accA[n] = MFMA16(aq, bk, accA[n]);
        }
    }
    __syncthreads();  // gcS/betaS ready
    half_t* attnB = attnW + (long)blk * 4096;
#pragma unroll
    for (int n = 0; n < 4; ++n)
#pragma unroll
        for (int e = 0; e < 4; ++e) {
            int i = w * 16 + hi * 4 + e;
            int j = n * 16 + lo;
            float dec = (j < i) ? expf(gcS[i] - gcS[j]) : 0.f;
            float av = (j < i) ? (-betaS[i] * accG[n][e] * dec) : (j == i ? 1.f : 0.f);
            at_wr(AT, i, j, av);
            attnB[(long)i * 64 + j] = (half_t)((j < i) ? accA[n][e] * dec : 0.f);
        }
    __syncthreads();
    if (w == 0) {
        // Register-resident forward substitution, fully unrolled.
        // lane = column j; t[i] = T[i][j].  T[i][j] = d_ij + sum_{p<i} A[i][p]*T[p][j]
        // (A row reads are wave-uniform -> broadcast; diag of AT holds 1.0 but
        //  p==i terms are excluded by compile-time guards.)
        float t[64];
#pragma unroll
        for (int i = 0; i < 64; ++i) t[i] = (lane == i) ? 1.f : 0.f;
#pragma unroll
        for (int i = 1; i < 64; ++i) {
            float a0 = 0.f, a1 = 0.f, a2 = 0.f, a3 = 0.f;
#pragma unroll
            for (int p0 = 0; p0 < i; p0 += 4) {
                f32x4 a4 = *(const f32x4*)((const char*)AT + i * 256 +
                                           ((p0 * 4) ^ ((i & 7) << 4)));
                if (p0 + 0 < i) a0 += a4[0] * t[p0 + 0];
                if (p0 + 1 < i) a1 += a4[1] * t[p0 + 1];
                if (p0 + 2 < i) a2 += a4[2] * t[p0 + 2];
                if (p0 + 3 < i) a3 += a4[3] * t[p0 + 3];
            }
            t[i] += (a0 + a1) + (a2 + a3);
        }
        // Write T as f16 rows (128 B, frag64 layout) into the dead A buffer.
        half_t* TS = (half_t*)AT;
#pragma unroll
        for (int i = 0; i < 64; ++i)
            *(half_t*)((char*)TS + i * 128 + ((lane * 2) ^ ((i & 7) << 4))) = (half_t)t[i];
    } else {
        // build XT (transposed operands), overlapped with the solve
        for (int idx = tid - 64; idx < 4096; idx += 192) {
            int p = idx >> 6, dp = idx & 63;
            float bb = betaS[p], be = betaS[p] * egS[p];
            half2_t vv = *(const half2_t*)(vb + (rowbase + p) * 4096 + vh * 128 + dp * 2);
            half2_t kk = *(const half2_t*)(kb + (rowbase + p) * 2048 + kh * 128 + dp * 2);
            w64(XT, dp * 2,       p, (float)vv[0] * bb);
            w64(XT, dp * 2 + 1,   p, (float)vv[1] * bb);
            w64(XT, 128 + dp * 2,     p, (float)kk[0] * be);
            w64(XT, 128 + dp * 2 + 1, p, (float)kk[1] * be);
        }
    }
    __syncthreads();
    // [v_t | kc] = T @ [v*beta | k*beta*e^g]  (wave w -> output cols 64w..64w+63)
    const half_t* TS = (const half_t*)AT;
    f32x4 accO[4][4] = {};
#pragma unroll
    for (int kt = 0; kt < 2; ++kt) {
        half8 tf[4];
#pragma unroll
        for (int m = 0; m < 4; ++m) tf[m] = frag64(TS, m * 16 + lo, kt * 32 + hi * 8);
#pragma unroll
        for (int n = 0; n < 4; ++n) {
            half8 bx = frag64(XT, w * 64 + n * 16 + lo, kt * 32 + hi * 8);
#pragma unroll
            for (int m = 0; m < 4; ++m) accO[m][n] = MFMA16(tf[m], bx, accO[m][n]);
        }
    }
    long ob = (long)blk * 8192;
#pragma unroll
    for (int m = 0; m < 4; ++m)
#pragma unroll
        for (int n = 0; n < 4; ++n)
#pragma unroll
            for (int e = 0; e < 4; ++e) {
                int i = m * 16 + hi * 4 + e;
                int dc = w * 64 + n * 16 + lo;
                float v = accO[m][n][e];
                if (dc < 128) vtW[ob + (long)i * 128 + dc] = (half_t)v;
                else          kcW[ob + (long)i * 128 + dc - 128] = (half_t)(-v);  // store -kc
            }
}

// ---------------------------------------------------------------------------
// Phase 2 (R2): sequential chunk scan per (b,vh,DV-slice of 32). grid 256
// (js in high bits so the 4 slices of one bvh share an XCD/L2). State^T
// slice (32x128 f16) in LDS; register double-buffered operand prefetch.
// ---------------------------------------------------------------------------
struct P2Ops {
    half8 kcf[4], qf[4], k8[4];
    half8 atf[2];
    half_t vtv[8];
    float gm, gi, g63;
};

__global__ __launch_bounds__(256, 1) void phase2_k(const half_t* __restrict__ qb,
                                                   const half_t* __restrict__ kb,
                                                   const float* __restrict__ gcum,
                                                   const half_t* __restrict__ attnW,
                                                   const half_t* __restrict__ vtW,
                                                   const half_t* __restrict__ kcW,
                                                   half_t* __restrict__ coreH) {
    __shared__ half_t SHs[32 * 128];  // S^T slice rows j (256 B, swizzled)
    __shared__ half_t vnT[32 * 64];   // v_new^T rows j (128 B, swizzled)
    __shared__ half_t kdT[128 * 64];  // kd rows d (128 B, swizzled)
    int blk = blockIdx.x;
    int bvh = blk & 63, js = blk >> 6;   // js slowest -> same XCD per bvh
    int vh = bvh & 31, b = bvh >> 5, kh = vh >> 1;
    int j0 = js * 32;
    int tid = threadIdx.x, lane = tid & 63, w = tid >> 6, lo = lane & 15, hi = lane >> 4;
    int ii = tid >> 2, dseg = tid & 3;   // kdT-build ownership
    int jm = w >> 1, dql = (w & 1) * 4;  // update-tile ownership
    for (int idx = tid; idx < 32 * 128; idx += 256) SHs[idx] = (half_t)0.f;
    __syncthreads();
    const float* gbase = gcum + (long)bvh * 4096;

    auto loadops = [&](int c, P2Ops& o) {
        long pb = (long)bvh * 64 + c;
        const half_t* kcG = kcW + pb * 8192;   // holds -kc
        const half_t* vtG = vtW + pb * 8192;
        const half_t* atG = attnW + pb * 4096;
        long rowbase = (long)b * 4096 + c * 64;
        const float* gp = gbase + c * 64;
#pragma unroll
        for (int kt = 0; kt < 4; ++kt) {
            o.kcf[kt] = *(const half8*)(kcG + (long)(w * 16 + lo) * 128 + kt * 32 + hi * 8);
            o.qf[kt] = *(const half8*)(qb + (rowbase + w * 16 + lo) * 2048 + kh * 128 +
                                       kt * 32 + hi * 8);
        }
#pragma unroll
        for (int kt2 = 0; kt2 < 2; ++kt2)
            o.atf[kt2] = *(const half8*)(atG + (long)(w * 16 + lo) * 64 + kt2 * 32 + hi * 8);
#pragma unroll
        for (int s = 0; s < 4; ++s)
            o.k8[s] = *(const half8*)(kb + (rowbase + ii) * 2048 + kh * 128 + dseg * 32 + s * 8);
#pragma unroll
        for (int n = 0; n < 2; ++n)
#pragma unroll
            for (int e = 0; e < 4; ++e)
                o.vtv[n * 4 + e] = vtG[(long)(w * 16 + hi * 4 + e) * 128 + j0 + n * 16 + lo];
        o.gm = gp[w * 16 + lo];
        o.gi = gp[ii];
        o.g63 = gp[63];
    };

    auto step = [&](int c, P2Ops& o, P2Ops& nx) {
        long rowbase = (long)b * 4096 + c * 64;
        loadops(c + 1 < 64 ? c + 1 : 63, nx);  // prefetch (hidden under MFMAs)
        // ---- S-slice fragments (reused for kc@S and q@S) ----
        half8 bS[4][2];
#pragma unroll
        for (int kt = 0; kt < 4; ++kt) {
            bS[kt][0] = frag128(SHs, lo, kt * 32 + hi * 8);
            bS[kt][1] = frag128(SHs, 16 + lo, kt * 32 + hi * 8);
        }
        // ---- v_new = v_t + (-kc)@S  (wave w owns i-tile w; n = j tiles) ----
        f32x4 accV[2];
#pragma unroll
        for (int n = 0; n < 2; ++n)
#pragma unroll
            for (int e = 0; e < 4; ++e) accV[n][e] = (float)o.vtv[n * 4 + e];
#pragma unroll
        for (int kt = 0; kt < 4; ++kt) {
            accV[0] = MFMA16(o.kcf[kt], bS[kt][0], accV[0]);
            accV[1] = MFMA16(o.kcf[kt], bS[kt][1], accV[1]);
        }
        // write v_new^T to LDS (C layout: col j = n*16+lo, rows i0..i0+3 contig)
#pragma unroll
        for (int n = 0; n < 2; ++n) {
            int j = n * 16 + lo, i0 = w * 16 + hi * 4;
            half4_t h4;
            h4[0] = (half_t)accV[n][0]; h4[1] = (half_t)accV[n][1];
            h4[2] = (half_t)accV[n][2]; h4[3] = (half_t)accV[n][3];
            *(half4_t*)((char*)vnT + j * 128 + ((i0 * 2) ^ ((j & 7) << 4))) = h4;
        }
        // build kdT[d][i] = k[i][d]*exp(g63-g_i) (thread owns i=ii, d-seg dseg)
        {
            float ek = expf(o.g63 - o.gi);
#pragma unroll
            for (int s = 0; s < 4; ++s)
#pragma unroll
                for (int e2 = 0; e2 < 8; ++e2)
                    w64(kdT, dseg * 32 + s * 8 + e2, ii, (float)o.k8[s][e2] * ek);
        }
        __syncthreads();  // S1: vnT, kdT ready
        // ---- out = (q*e^g)@S + attn@v_new ----
        float egm = expf(o.gm);
        f32x4 accO[2] = {};
#pragma unroll
        for (int kt = 0; kt < 4; ++kt) {
            half8 aq;
#pragma unroll
            for (int e2 = 0; e2 < 8; ++e2) aq[e2] = (half_t)((float)o.qf[kt][e2] * egm);
            accO[0] = MFMA16(aq, bS[kt][0], accO[0]);
            accO[1] = MFMA16(aq, bS[kt][1], accO[1]);
        }
#pragma unroll
        for (int kt2 = 0; kt2 < 2; ++kt2) {
            half8 bV0 = frag64(vnT, lo, kt2 * 32 + hi * 8);
            half8 bV1 = frag64(vnT, 16 + lo, kt2 * 32 + hi * 8);
            accO[0] = MFMA16(o.atf[kt2], bV0, accO[0]);
            accO[1] = MFMA16(o.atf[kt2], bV1, accO[1]);
        }
        // ---- update MFMAs: S^T_new -= ... (reads vnT/kdT only; RMW after S2)
        f32x4 accU[4] = {};
#pragma unroll
        for (int kt2 = 0; kt2 < 2; ++kt2) {
            half8 avn = frag64(vnT, jm * 16 + lo, kt2 * 32 + hi * 8);
#pragma unroll
            for (int dnn = 0; dnn < 4; ++dnn) {
                half8 bkd = frag64(kdT, (dql + dnn) * 16 + lo, kt2 * 32 + hi * 8);
                accU[dnn] = MFMA16(avn, bkd, accU[dnn]);
            }
        }
        // out store (no LDS dependence)
#pragma unroll
        for (int n = 0; n < 2; ++n)
#pragma unroll
            for (int e = 0; e < 4; ++e)
                coreH[(rowbase + w * 16 + hi * 4 + e) * 4096 + vh * 128 + j0 + n * 16 + lo] =
                    (half_t)accO[n][e];
        __syncthreads();  // S2: all q@S reads of SHs done
        float egl = expf(o.g63);
#pragma unroll
        for (int dnn = 0; dnn < 4; ++dnn)
#pragma unroll
            for (int e = 0; e < 4; ++e) {
                int j = jm * 16 + hi * 4 + e;
                int d = (dql + dnn) * 16 + lo;
                char* p = (char*)SHs + j * 256 + ((d * 2) ^ ((j & 7) << 4));
                float old = (float)*(half_t*)p;
                *(half_t*)p = (half_t)(old * egl + accU[dnn][e]);
            }
        __syncthreads();  // S3: state updated for next chunk
    };

    P2Ops opsA, opsB;
    loadops(0, opsA);
    for (int c = 0; c < 64; c += 2) {
        step(c, opsA, opsB);
        step(c + 1, opsB, opsA);
    }
}

// ---------------------------------------------------------------------------
// Gated RMSNorm + silu(z) gate, IN-PLACE on coreH. One wave per (b,s,vh) row.
// grid: 65536 (= B*S*HV/4 waves).
// ---------------------------------------------------------------------------
__global__ __launch_bounds__(256) void normgate_k(half_t* __restrict__ coreH,
                                                  const half_t* __restrict__ zH,
                                                  const float* __restrict__ norm_w) {
    int w = threadIdx.x >> 6, lane = threadIdx.x & 63;
    long rid = (long)blockIdx.x * 4 + w;  // < 262144
    long bs = rid >> 5;
    int vh = rid & 31;
    half_t* cr = coreH + bs * 4096 + vh * 128;
    half2_t cv = *(half2_t*)(cr + lane * 2);
    float f0 = (float)cv[0], f1 = (float)cv[1];
    float ss = f0 * f0 + f1 * f1;
#pragma unroll
    for (int off = 32; off; off >>= 1) ss += __shfl_xor(ss, off);
    float rs = rsqrtf(ss * (1.f / 128.f) + 1e-6f);
    half2_t zz = *(const half2_t*)(zH + bs * 4096 + vh * 128 + lane * 2);
    float z0 = (float)zz[0], z1 = (float)zz[1];
    float s0 = z0 / (1.f + expf(-z0)), s1 = z1 / (1.f + expf(-z1));
    float w0 = norm_w[lane * 2], w1 = norm_w[lane * 2 + 1];
    half2_t o;
    o[0] = (half_t)(f0 * rs * w0 * s0);
    o[1] = (half_t)(f1 * rs * w1 * s1);
    *(half2_t*)(cr + lane * 2) = o;
}

// ---------------------------------------------------------------------------
// Host launcher.  Workspace layout (MiB offsets), hand-aliased, peak 370 MiB:
//   [0,32)    qb          (conv..phase2)   | overlay: hiddenH (cast..gemm1)
//   [32,64)   kb          (conv..phase2)   | overlay: W1T head
//   [64,128)  vb          (conv..phase1)   | overlay: W1T tail [64,81);
//                                            later coreH (phase2..gemm2)
//   [128,129) betaB   [129,130) gcum
//   [130,146) WoT         (build..gemm2)
//   [146,210) zH          (gemm1b..normgate)
//   [210,340) mixedH      (gemm1a..gate)   | overlay after: attnW [210,242),
//   [340,370)                                vtW [242,306), kcW [306,370)
// ---------------------------------------------------------------------------
extern "C" void kernel_launch(void* const* d_in, const int* in_sizes, int n_in,
                              void* d_out, int out_size, void* d_ws, size_t ws_size,
                              hipStream_t stream) {
    const float* hidden  = (const float*)d_in[0];
    const float* W_qkvz  = (const float*)d_in[1];
    const float* W_ba    = (const float*)d_in[2];
    const float* conv_w  = (const float*)d_in[3];
    const float* A_log   = (const float*)d_in[4];
    const float* dt_bias = (const float*)d_in[5];
    const float* norm_w  = (const float*)d_in[6];
    const float* W_out   = (const float*)d_in[7];
    float* out = (float*)d_out;

    char* ws = (char*)d_ws;
    const size_t MB = 1ull << 20;
    half_t* qb      = (half_t*)(ws + 0);
    half_t* kb      = (half_t*)(ws + 32 * MB);
    half_t* vb      = (half_t*)(ws + 64 * MB);
    float*  betaB   = (float*) (ws + 128 * MB);
    float*  gcum    = (float*) (ws + 129 * MB);
    half_t* WoT     = (half_t*)(ws + 130 * MB);
    half_t* zH      = (half_t*)(ws + 146 * MB);
    half_t* mixedH  = (half_t*)(ws + 210 * MB);
    half_t* attnW   = (half_t*)(ws + 210 * MB);  // overlays dead mixedH
    half_t* vtW     = (half_t*)(ws + 242 * MB);
    half_t* kcW     = (half_t*)(ws + 306 * MB);
    half_t* hiddenH = (half_t*)(ws + 0);         // overlays not-yet-written qb
    half_t* W1T     = (half_t*)(ws + 32 * MB);   // overlays kb + head of vb
    half_t* coreH   = (half_t*)(ws + 64 * MB);   // overlays dead vb
    (void)ws_size; (void)in_sizes; (void)n_in; (void)out_size;

    // 1. casts / transposes
    cast_h_k<<<16384, 256, 0, stream>>>(hidden, hiddenH);
    build_w1t_k<<<dim3(388, 64), 256, 0, stream>>>(W_qkvz, W_ba, W1T);
    build_wot_k<<<dim3(64, 128), 256, 0, stream>>>(W_out, WoT);
    // 2. fused projection, split: qkv+ba (N=8320) then z (N=4096); K=2048
    gemm_k<1><<<dim3(64, 65), 256, 0, stream>>>(hiddenH, W1T, mixedH, 2048, 8320);
    gemm_k<1><<<dim3(64, 32), 256, 0, stream>>>(hiddenH, W1T + (size_t)8320 * 2048, zH,
                                                2048, 4096);
    // 3. conv + silu ; gates ; l2norm
    conv_silu_k<<<dim3(32, 64), 256, 0, stream>>>(mixedH, conv_w, qb, kb, vb);
    gate_beta_k<<<128, 256, 0, stream>>>(mixedH, A_log, dt_bias, betaB, gcum);
    l2norm_k<<<65536, 256, 0, stream>>>(qb, kb);
    // 4. delta-rule core
    phase1_k<<<4096, 256, 0, stream>>>(qb, kb, vb, betaB, gcum, attnW, vtW, kcW);
    phase2_k<<<256, 256, 0, stream>>>(qb, kb, gcum, attnW, vtW, kcW, coreH);
    // 5. gated RMSNorm (in-place) + output projection (M=8192, N=2048, K=4096)
    normgate_k<<<65536, 256, 0, stream>>>(coreH, zH, norm_w);
    gemm_k<0><<<dim3(64, 16), 256, 0, stream>>>(coreH, WoT, out, 4096, 2048);
}

// Round 5
// 1272.485 us; speedup vs baseline: 1.9389x; 1.0878x over previous
//
#include <hip/hip_runtime.h>
#include <cstdint>
#include <cstddef>

// ---------------------------------------------------------------------------
// Qwen3.5 GatedDeltaNet forward, MI355X (gfx950), f16-MFMA implementation.
// B=2, S=4096, H=2048, HK=16, HV=32, DK=DV=128, KW=4, CS=64.
// R2: phase2 split 4x across DV (grid 64 -> 256), reg-prefetch.
// R3: phase1 register-resident forward substitution.
// R4: all three GEMMs -> 256x256 8-phase template (8 waves, BK=64, counted
//     vmcnt(6), raw s_barrier, setprio, XOR-swizzled LDS via pre-swizzled
//     global source, bijective XCD swizzle). N of gemm1 padded to 8448.
// ---------------------------------------------------------------------------

typedef _Float16 half_t;
typedef _Float16 half2_t __attribute__((ext_vector_type(2)));
typedef _Float16 half4_t __attribute__((ext_vector_type(4)));
typedef _Float16 half8   __attribute__((ext_vector_type(8)));
typedef float    f32x4   __attribute__((ext_vector_type(4)));

#define MFMA16(a, b, c) __builtin_amdgcn_mfma_f32_16x16x32_f16((a), (b), (c), 0, 0, 0)

#define AS1 __attribute__((address_space(1)))
#define AS3 __attribute__((address_space(3)))

__device__ __forceinline__ void gload16(void* lds, const void* g) {
    __builtin_amdgcn_global_load_lds((AS1 void*)(g), (AS3 void*)(lds), 16, 0, 0);
}

// ---- swizzled-LDS access helpers (XOR byte-bits 4..6 with row&7) ----------
__device__ __forceinline__ void at_wr(float* AT, int i, int j, float v) {
    *(float*)((char*)AT + i * 256 + ((j * 4) ^ ((i & 7) << 4))) = v;
}
__device__ __forceinline__ half8 frag64(const half_t* base, int row, int koff) {
    return *(const half8*)((const char*)base + row * 128 + ((koff * 2) ^ ((row & 7) << 4)));
}
__device__ __forceinline__ void w64(half_t* base, int row, int col, float v) {
    *(half_t*)((char*)base + row * 128 + ((col * 2) ^ ((row & 7) << 4))) = (half_t)v;
}
__device__ __forceinline__ half8 frag128(const half_t* base, int row, int koff) {
    return *(const half8*)((const char*)base + row * 256 + ((koff * 2) ^ ((row & 7) << 4)));
}

// ---------------------------------------------------------------------------
// Cast / transpose prep kernels
// ---------------------------------------------------------------------------
__global__ __launch_bounds__(256) void cast_h_k(const float* __restrict__ src,
                                                half_t* __restrict__ dst) {
    long i = (long)blockIdx.x * 256 + threadIdx.x;
    f32x4 v = *(const f32x4*)(src + i * 4);
    half4_t h;
    h[0] = (half_t)v[0]; h[1] = (half_t)v[1]; h[2] = (half_t)v[2]; h[3] = (half_t)v[3];
    *(half4_t*)(dst + i * 4) = h;
}

// Column-permuted W1T[n][k], n < 12544:
//   [0,2048) q | [2048,4096) k | [4096,8192) v | [8192,8256) ba |
//   [8256,8448) zero pad | [8448,12544) z
__global__ __launch_bounds__(256) void build_w1t_k(const float* __restrict__ Wq,
                                                   const float* __restrict__ Wba,
                                                   half_t* __restrict__ W1T) {
    __shared__ half_t tile[32][33];
    int n0 = blockIdx.x * 32, k0 = blockIdx.y * 32;
    int tx = threadIdx.x & 31, ty = threadIdx.x >> 5;
#pragma unroll
    for (int t = 0; t < 4; ++t) {
        int k = k0 + ty + t * 8, n = n0 + tx;
        float v = 0.f;
        if (n < 2048) {
            int kh = n >> 7, d = n & 127;
            v = Wq[(long)k * 12288 + kh * 768 + d];
        } else if (n < 4096) {
            int n2 = n - 2048; int kh = n2 >> 7, d = n2 & 127;
            v = Wq[(long)k * 12288 + kh * 768 + 128 + d];
        } else if (n < 8192) {
            int n3 = n - 4096; int vh = n3 >> 7, d = n3 & 127;
            int kh = vh >> 1, jj = vh & 1;
            v = Wq[(long)k * 12288 + kh * 768 + 256 + jj * 128 + d];
        } else if (n < 8256) {
            v = Wba[(long)k * 64 + (n - 8192)];
        } else if (n >= 8448) {
            int n4 = n - 8448; int vh = n4 >> 7, d = n4 & 127;
            int kh = vh >> 1, jj = vh & 1;
            v = Wq[(long)k * 12288 + kh * 768 + 512 + jj * 128 + d];
        }
        tile[ty + t * 8][tx] = (half_t)v;
    }
    __syncthreads();
#pragma unroll
    for (int t = 0; t < 4; ++t) {
        int n = n0 + ty + t * 8, k = k0 + tx;
        W1T[(long)n * 2048 + k] = tile[tx][ty + t * 8];
    }
}

// WoT[n][k] = W_out[k][n]; n < 2048, k < 4096
__global__ __launch_bounds__(256) void build_wot_k(const float* __restrict__ Wo,
                                                   half_t* __restrict__ WoT) {
    __shared__ half_t tile[32][33];
    int n0 = blockIdx.x * 32, k0 = blockIdx.y * 32;
    int tx = threadIdx.x & 31, ty = threadIdx.x >> 5;
#pragma unroll
    for (int t = 0; t < 4; ++t) {
        int k = k0 + ty + t * 8, n = n0 + tx;
        tile[ty + t * 8][tx] = (half_t)Wo[(long)k * 2048 + n];
    }
    __syncthreads();
#pragma unroll
    for (int t = 0; t < 4; ++t) {
        int n = n0 + ty + t * 8, k = k0 + tx;
        WoT[(long)n * 4096 + k] = tile[tx][ty + t * 8];
    }
}

// ---------------------------------------------------------------------------
// 256x256 8-phase f16 GEMM: C = A(MxK) * Bt(NxK)^T.  512 threads (8 waves,
// 2M x 4N), BK=64, LDS 128 KiB (2 dbuf x {A,B} x 2 half-tiles of 128x64).
// Counted vmcnt(6) at phases 4/8 only; raw s_barrier; setprio around MFMA.
// Stage schedule keeps >=1 full barrier between a half-tile's last LDS read
// and its overwriting global_load_lds. Grid must be divisible by 8 (XCD swz).
// ---------------------------------------------------------------------------
template <int OUT_F16>
__global__ __launch_bounds__(512, 2) void gemm256_k(const half_t* __restrict__ A,
                                                    const half_t* __restrict__ Bt,
                                                    void* __restrict__ C,
                                                    int K, int ldc, int nwgM) {
    __shared__ half_t LA[2][2][8192];   // [buf][half][128 rows x 64 f16]
    __shared__ half_t LB[2][2][8192];
    const int tid = threadIdx.x, lane = tid & 63, w = tid >> 6;
    const int lo = lane & 15, hi = lane >> 4;
    const int wm = w >> 2, wn = w & 3;
    // bijective XCD swizzle (gridDim.x % 8 == 0)
    const int nwg = gridDim.x, q = nwg >> 3, bid = blockIdx.x;
    const int swz = (bid & 7) * q + (bid >> 3);
    const long tm = swz % nwgM, tn = swz / nwgM;
    const long Kb = (long)K * 2;
    const char* Ab = (const char*)A + tm * 256 * Kb;
    const char* Bb = (const char*)Bt + tn * 256 * Kb;
    // stage geometry: wave w writes LDS segs s0,s1 (1 KiB each, linear);
    // source column pre-swizzled so swizzled reads see logical data (rule 21).
    const int scol = ((lane & 7) << 4) ^ ((lane >> 3) << 4);
    const int srow = lane >> 3;
    const int s0 = w * 2, s1 = w * 2 + 1;

    auto stA = [&](int kt, int h) {
        char* hb = (char*)&LA[kt & 1][h][0];
        const char* gb = Ab + (long)(h * 128) * Kb + (long)kt * 128;
        gload16(hb + s0 * 1024, gb + (long)(s0 * 8 + srow) * Kb + scol);
        gload16(hb + s1 * 1024, gb + (long)(s1 * 8 + srow) * Kb + scol);
    };
    auto stB = [&](int kt, int h) {
        char* hb = (char*)&LB[kt & 1][h][0];
        const char* gb = Bb + (long)(h * 128) * Kb + (long)kt * 128;
        gload16(hb + s0 * 1024, gb + (long)(s0 * 8 + srow) * Kb + scol);
        gload16(hb + s1 * 1024, gb + (long)(s1 * 8 + srow) * Kb + scol);
    };
    auto rdA = [&](int p, int mt, int ks) -> half8 {
        int r = mt * 16 + lo;
        return *(const half8*)((const char*)&LA[p][wm][0] + r * 128 +
                               ((ks * 64 + hi * 16) ^ ((r & 7) << 4)));
    };
    auto rdB = [&](int p, int nt, int ks) -> half8 {
        int r = (wn & 1) * 64 + nt * 16 + lo;
        return *(const half8*)((const char*)&LB[p][wn >> 1][0] + r * 128 +
                               ((ks * 64 + hi * 16) ^ ((r & 7) << 4)));
    };

    f32x4 acc[8][4] = {};
    half8 af[4][2], bfa[2][2], bfb[2][2];

    auto ldsA4 = [&](int p, int mbase) {
#pragma unroll
        for (int mt = 0; mt < 4; ++mt) {
            af[mt][0] = rdA(p, mbase + mt, 0);
            af[mt][1] = rdA(p, mbase + mt, 1);
        }
    };
    auto ldsB2 = [&](int p, int nbase, half8 (&dst)[2][2]) {
#pragma unroll
        for (int nt = 0; nt < 2; ++nt) {
            dst[nt][0] = rdB(p, nbase + nt, 0);
            dst[nt][1] = rdB(p, nbase + nt, 1);
        }
    };
    auto quad = [&](const half8 (&bq)[2][2], int mo, int no) {
        __builtin_amdgcn_s_setprio(1);
#pragma unroll
        for (int mt = 0; mt < 4; ++mt)
#pragma unroll
            for (int nt = 0; nt < 2; ++nt) {
                acc[mo + mt][no + nt] = MFMA16(af[mt][0], bq[nt][0], acc[mo + mt][no + nt]);
                acc[mo + mt][no + nt] = MFMA16(af[mt][1], bq[nt][1], acc[mo + mt][no + nt]);
            }
        __builtin_amdgcn_s_setprio(0);
        __builtin_amdgcn_s_barrier();
    };

    const int nkt = K >> 6, niter = nkt >> 1;
    // prologue: K-tile 0 complete + K-tile 1 halves A0,B0,B1 (A1 at ph1)
    stA(0, 0); stA(0, 1); stB(0, 0); stB(0, 1);
    stA(1, 0); stB(1, 0); stB(1, 1);
    asm volatile("s_waitcnt vmcnt(6)" ::: "memory");
    __builtin_amdgcn_s_barrier();

    for (int i = 0; i < niter; ++i) {
        const int k0 = 2 * i, k1 = 2 * i + 1;
        const bool sa = (k0 + 2 < nkt), sb = (k1 + 2 < nkt);
        // ph1: Q(a0,b0) on k0 | stage (k1).A-hi
        ldsA4(0, 0); ldsB2(0, 0, bfa);
        stA(k1, 1);
        __builtin_amdgcn_s_barrier();
        quad(bfa, 0, 0);
        // ph2: Q(a0,b1) | B halves retire here
        ldsB2(0, 2, bfb);
        __builtin_amdgcn_s_barrier();
        quad(bfb, 0, 2);
        // ph3: Q(a1,b0) | A halves retire here | stage (k0+2).B-lo
        ldsA4(0, 4);
        if (sa) stB(k0 + 2, 0);
        __builtin_amdgcn_s_barrier();
        quad(bfa, 4, 0);
        // ph4: Q(a1,b1) | stage (k0+2).A-lo,.B-hi | counted vmcnt
        if (sa) {
            stA(k0 + 2, 0); stB(k0 + 2, 1);
            asm volatile("s_waitcnt vmcnt(6)" ::: "memory");
        } else {
            asm volatile("s_waitcnt vmcnt(0)" ::: "memory");
        }
        __builtin_amdgcn_s_barrier();
        quad(bfb, 4, 2);
        // ph5: Q(a0,b0) on k1 | stage (k0+2).A-hi
        ldsA4(1, 0); ldsB2(1, 0, bfa);
        if (sa) stA(k0 + 2, 1);
        __builtin_amdgcn_s_barrier();
        quad(bfa, 0, 0);
        // ph6: Q(a0,b1)
        ldsB2(1, 2, bfb);
        __builtin_amdgcn_s_barrier();
        quad(bfb, 0, 2);
        // ph7: Q(a1,b0) | stage (k1+2).B-lo
        ldsA4(1, 4);
        if (sb) stB(k1 + 2, 0);
        __builtin_amdgcn_s_barrier();
        quad(bfa, 4, 0);
        // ph8: Q(a1,b1) | stage (k1+2).A-lo,.B-hi | counted vmcnt
        if (sb) {
            stA(k1 + 2, 0); stB(k1 + 2, 1);
            asm volatile("s_waitcnt vmcnt(6)" ::: "memory");
        }
        __builtin_amdgcn_s_barrier();
        quad(bfb, 4, 2);
    }

    const long crow0 = tm * 256 + wm * 128 + hi * 4;
    const long ccol0 = tn * 256 + wn * 64 + lo;
#pragma unroll
    for (int mt = 0; mt < 8; ++mt)
#pragma unroll
        for (int nt = 0; nt < 4; ++nt)
#pragma unroll
            for (int e = 0; e < 4; ++e) {
                long row = crow0 + mt * 16 + e;
                long col = ccol0 + nt * 16;
                if (OUT_F16)
                    ((half_t*)C)[row * (long)ldc + col] = (half_t)acc[mt][nt][e];
                else
                    ((float*)C)[row * (long)ldc + col] = acc[mt][nt][e];
            }
}

// ---------------------------------------------------------------------------
// Causal depthwise conv (KW=4) + SiLU over mixed (B,S,8448) channels 0..8191.
// ---------------------------------------------------------------------------
__global__ __launch_bounds__(256) void conv_silu_k(const half_t* __restrict__ mixedH,
                                                   const float* __restrict__ conv_w,
                                                   half_t* __restrict__ qb,
                                                   half_t* __restrict__ kb,
                                                   half_t* __restrict__ vb) {
    int ch = blockIdx.x * 256 + threadIdx.x;
    int b = blockIdx.y >> 5, sc = blockIdx.y & 31;
    int s0 = sc * 128;
    half_t* dptr;
    long dstr;
    if (ch < 2048)      { dptr = qb + ch;          dstr = 2048; }
    else if (ch < 4096) { dptr = kb + (ch - 2048); dstr = 2048; }
    else                { dptr = vb + (ch - 4096); dstr = 4096; }
    float w0 = conv_w[ch * 4 + 0], w1 = conv_w[ch * 4 + 1];
    float w2 = conv_w[ch * 4 + 2], w3 = conv_w[ch * 4 + 3];
    const half_t* src = mixedH + (long)b * 4096 * 8448 + ch;
    float x0 = (s0 >= 3) ? (float)src[(long)(s0 - 3) * 8448] : 0.f;
    float x1 = (s0 >= 2) ? (float)src[(long)(s0 - 2) * 8448] : 0.f;
    float x2 = (s0 >= 1) ? (float)src[(long)(s0 - 1) * 8448] : 0.f;
    for (int s = s0; s < s0 + 128; ++s) {
        float x3 = (float)src[(long)s * 8448];
        float y = w0 * x0 + w1 * x1 + w2 * x2 + w3 * x3;
        y = y / (1.f + expf(-y));
        dptr[((long)b * 4096 + s) * dstr] = (half_t)y;
        x0 = x1; x1 = x2; x2 = x3;
    }
}

// ---------------------------------------------------------------------------
// beta = sigmoid(b), g = -exp(A_log)*softplus(a+dt_bias), per-chunk cumsum.
// ---------------------------------------------------------------------------
__global__ __launch_bounds__(256) void gate_beta_k(const half_t* __restrict__ mixedH,
                                                   const float* __restrict__ A_log,
                                                   const float* __restrict__ dt_bias,
                                                   float* __restrict__ beta,
                                                   float* __restrict__ gcum) {
    __shared__ float gs[32][64];
    int b = blockIdx.x >> 6, c = blockIdx.x & 63;
    for (int idx = threadIdx.x; idx < 2048; idx += 256) {
        int vh = idx & 31, i = idx >> 5;
        int kh = vh >> 1, j = vh & 1;
        long row = ((long)b * 4096 + c * 64 + i) * 8448 + 8192 + kh * 4;
        float bb = (float)mixedH[row + j];
        float aa = (float)mixedH[row + 2 + j];
        beta[((long)b * 4096 + c * 64 + i) * 32 + vh] = 1.f / (1.f + expf(-bb));
        float x = aa + dt_bias[vh];
        float sp = (x > 15.f) ? x : log1pf(expf(x));
        gs[vh][i] = -expf(A_log[vh]) * sp;
    }
    __syncthreads();
    if (threadIdx.x < 32) {
        int vh = threadIdx.x;
        float cum = 0.f;
        float* gout = gcum + ((long)(b * 32 + vh)) * 4096 + c * 64;
        for (int i = 0; i < 64; ++i) { cum += gs[vh][i]; gout[i] = cum; }
    }
}

// ---------------------------------------------------------------------------
// l2norm rows of 128 (in-place, f16). q rows get extra 1/sqrt(128).
// ---------------------------------------------------------------------------
__global__ __launch_bounds__(256) void l2norm_k(half_t* __restrict__ qb,
                                                half_t* __restrict__ kb) {
    int w = threadIdx.x >> 6, lane = threadIdx.x & 63;
    long rid = (long)blockIdx.x * 4 + w;
    half_t* base;
    float sc;
    if (rid < 131072) { base = qb + rid * 128; sc = 0.08838834764831845f; }
    else              { base = kb + (rid - 131072) * 128; sc = 1.f; }
    half2_t hv = *(half2_t*)(base + lane * 2);
    float f0 = (float)hv[0], f1 = (float)hv[1];
    float ss = f0 * f0 + f1 * f1;
#pragma unroll
    for (int off = 32; off; off >>= 1) ss += __shfl_xor(ss, off);
    float r = rsqrtf(ss + 1e-6f) * sc;
    half2_t o; o[0] = (half_t)(f0 * r); o[1] = (half_t)(f1 * r);
    *(half2_t*)(base + lane * 2) = o;
}

// ---------------------------------------------------------------------------
// Phase 1: per (b,vh,chunk): A, T=(I-A)^-1, attn, v_t, -kc.  grid 4096.
// ---------------------------------------------------------------------------
__global__ __launch_bounds__(256) void phase1_k(const half_t* __restrict__ qb,
                                                const half_t* __restrict__ kb,
                                                const half_t* __restrict__ vb,
                                                const float* __restrict__ beta,
                                                const float* __restrict__ gcum,
                                                half_t* __restrict__ attnW,
                                                half_t* __restrict__ vtW,
                                                half_t* __restrict__ kcW) {
    __shared__ float AT[64 * 64];       // swizzled rows (256 B); A f32, then T f16
    __shared__ half_t XT[256 * 64];     // rows 0..127 = (v*beta)^T, 128..255 = (k*beta*e^g)^T
    __shared__ float gcS[64], betaS[64], egS[64];
    int blk = blockIdx.x;
    int c = blk & 63, vh = (blk >> 6) & 31, b = blk >> 11;
    int kh = vh >> 1;
    int tid = threadIdx.x, lane = tid & 63, w = tid >> 6, lo = lane & 15, hi = lane >> 4;
    long rowbase = (long)b * 4096 + c * 64;
    if (tid < 64) {
        float g = gcum[((long)(b * 32 + vh)) * 4096 + c * 64 + tid];
        gcS[tid] = g; egS[tid] = expf(g);
        betaS[tid] = beta[(rowbase + tid) * 32 + vh];
    }
    const half_t* kR = kb + rowbase * 2048 + kh * 128;
    const half_t* qR = qb + rowbase * 2048 + kh * 128;
    f32x4 accG[4] = {}, accA[4] = {};
#pragma unroll
    for (int kt = 0; kt < 4; ++kt) {
        half8 ak = *(const half8*)(kR + (long)(w * 16 + lo) * 2048 + kt * 32 + hi * 8);
        half8 aq = *(const half8*)(qR + (long)(w * 16 + lo) * 2048 + kt * 32 + hi * 8);
#pragma unroll
        for (int n = 0; n < 4; ++n) {
            half8 bk = *(const half8*)(kR + (long)(n * 16 + lo) * 2048 + kt * 32 + hi * 8);
            accG[n] = MFMA16(ak, bk, accG[n]);
            accA[n] = MFMA16(aq, bk, accA[n]);
        }
    }
    __syncthreads();
    half_t* attnB = attnW + (long)blk * 4096;
#pragma unroll
    for (int n = 0; n < 4; ++n)
#pragma unroll
        for (int e = 0; e < 4; ++e) {
            int i = w * 16 + hi * 4 + e;
            int j = n * 16 + lo;
            float dec = (j < i) ? expf(gcS[i] - gcS[j]) : 0.f;
            float av = (j < i) ? (-betaS[i] * accG[n][e] * dec) : (j == i ? 1.f : 0.f);
            at_wr(AT, i, j, av);
            attnB[(long)i * 64 + j] = (half_t)((j < i) ? accA[n][e] * dec : 0.f);
        }
    __syncthreads();
    if (w == 0) {
        float t[64];
#pragma unroll
        for (int i = 0; i < 64; ++i) t[i] = (lane == i) ? 1.f : 0.f;
#pragma unroll
        for (int i = 1; i < 64; ++i) {
            float a0 = 0.f, a1 = 0.f, a2 = 0.f, a3 = 0.f;
#pragma unroll
            for (int p0 = 0; p0 < i; p0 += 4) {
                f32x4 a4 = *(const f32x4*)((const char*)AT + i * 256 +
                                           ((p0 * 4) ^ ((i & 7) << 4)));
                if (p0 + 0 < i) a0 += a4[0] * t[p0 + 0];
                if (p0 + 1 < i) a1 += a4[1] * t[p0 + 1];
                if (p0 + 2 < i) a2 += a4[2] * t[p0 + 2];
                if (p0 + 3 < i) a3 += a4[3] * t[p0 + 3];
            }
            t[i] += (a0 + a1) + (a2 + a3);
        }
        half_t* TS = (half_t*)AT;
#pragma unroll
        for (int i = 0; i < 64; ++i)
            *(half_t*)((char*)TS + i * 128 + ((lane * 2) ^ ((i & 7) << 4))) = (half_t)t[i];
    } else {
        for (int idx = tid - 64; idx < 4096; idx += 192) {
            int p = idx >> 6, dp = idx & 63;
            float bb = betaS[p], be = betaS[p] * egS[p];
            half2_t vv = *(const half2_t*)(vb + (rowbase + p) * 4096 + vh * 128 + dp * 2);
            half2_t kk = *(const half2_t*)(kb + (rowbase + p) * 2048 + kh * 128 + dp * 2);
            w64(XT, dp * 2,       p, (float)vv[0] * bb);
            w64(XT, dp * 2 + 1,   p, (float)vv[1] * bb);
            w64(XT, 128 + dp * 2,     p, (float)kk[0] * be);
            w64(XT, 128 + dp * 2 + 1, p, (float)kk[1] * be);
        }
    }
    __syncthreads();
    const half_t* TS = (const half_t*)AT;
    f32x4 accO[4][4] = {};
#pragma unroll
    for (int kt = 0; kt < 2; ++kt) {
        half8 tf[4];
#pragma unroll
        for (int m = 0; m < 4; ++m) tf[m] = frag64(TS, m * 16 + lo, kt * 32 + hi * 8);
#pragma unroll
        for (int n = 0; n < 4; ++n) {
            half8 bx = frag64(XT, w * 64 + n * 16 + lo, kt * 32 + hi * 8);
#pragma unroll
            for (int m = 0; m < 4; ++m) accO[m][n] = MFMA16(tf[m], bx, accO[m][n]);
        }
    }
    long ob = (long)blk * 8192;
#pragma unroll
    for (int m = 0; m < 4; ++m)
#pragma unroll
        for (int n = 0; n < 4; ++n)
#pragma unroll
            for (int e = 0; e < 4; ++e) {
                int i = m * 16 + hi * 4 + e;
                int dc = w * 64 + n * 16 + lo;
                float v = accO[m][n][e];
                if (dc < 128) vtW[ob + (long)i * 128 + dc] = (half_t)v;
                else          kcW[ob + (long)i * 128 + dc - 128] = (half_t)(-v);
            }
}

// ---------------------------------------------------------------------------
// Phase 2: sequential chunk scan per (b,vh,DV-slice of 32). grid 256.
// ---------------------------------------------------------------------------
struct P2Ops {
    half8 kcf[4], qf[4], k8[4];
    half8 atf[2];
    half_t vtv[8];
    float gm, gi, g63;
};

__global__ __launch_bounds__(256, 1) void phase2_k(const half_t* __restrict__ qb,
                                                   const half_t* __restrict__ kb,
                                                   const float* __restrict__ gcum,
                                                   const half_t* __restrict__ attnW,
                                                   const half_t* __restrict__ vtW,
                                                   const half_t* __restrict__ kcW,
                                                   half_t* __restrict__ coreH) {
    __shared__ half_t SHs[32 * 128];
    __shared__ half_t vnT[32 * 64];
    __shared__ half_t kdT[128 * 64];
    int blk = blockIdx.x;
    int bvh = blk & 63, js = blk >> 6;
    int vh = bvh & 31, b = bvh >> 5, kh = vh >> 1;
    int j0 = js * 32;
    int tid = threadIdx.x, lane = tid & 63, w = tid >> 6, lo = lane & 15, hi = lane >> 4;
    int ii = tid >> 2, dseg = tid & 3;
    int jm = w >> 1, dql = (w & 1) * 4;
    for (int idx = tid; idx < 32 * 128; idx += 256) SHs[idx] = (half_t)0.f;
    __syncthreads();
    const float* gbase = gcum + (long)bvh * 4096;

    auto loadops = [&](int c, P2Ops& o) {
        long pb = (long)bvh * 64 + c;
        const half_t* kcG = kcW + pb * 8192;
        const half_t* vtG = vtW + pb * 8192;
        const half_t* atG = attnW + pb * 4096;
        long rowbase = (long)b * 4096 + c * 64;
        const float* gp = gbase + c * 64;
#pragma unroll
        for (int kt = 0; kt < 4; ++kt) {
            o.kcf[kt] = *(const half8*)(kcG + (long)(w * 16 + lo) * 128 + kt * 32 + hi * 8);
            o.qf[kt] = *(const half8*)(qb + (rowbase + w * 16 + lo) * 2048 + kh * 128 +
                                       kt * 32 + hi * 8);
        }
#pragma unroll
        for (int kt2 = 0; kt2 < 2; ++kt2)
            o.atf[kt2] = *(const half8*)(atG + (long)(w * 16 + lo) * 64 + kt2 * 32 + hi * 8);
#pragma unroll
        for (int s = 0; s < 4; ++s)
            o.k8[s] = *(const half8*)(kb + (rowbase + ii) * 2048 + kh * 128 + dseg * 32 + s * 8);
#pragma unroll
        for (int n = 0; n < 2; ++n)
#pragma unroll
            for (int e = 0; e < 4; ++e)
                o.vtv[n * 4 + e] = vtG[(long)(w * 16 + hi * 4 + e) * 128 + j0 + n * 16 + lo];
        o.gm = gp[w * 16 + lo];
        o.gi = gp[ii];
        o.g63 = gp[63];
    };

    auto step = [&](int c, P2Ops& o, P2Ops& nx) {
        long rowbase = (long)b * 4096 + c * 64;
        loadops(c + 1 < 64 ? c + 1 : 63, nx);
        half8 bS[4][2];
#pragma unroll
        for (int kt = 0; kt < 4; ++kt) {
            bS[kt][0] = frag128(SHs, lo, kt * 32 + hi * 8);
            bS[kt][1] = frag128(SHs, 16 + lo, kt * 32 + hi * 8);
        }
        f32x4 accV[2];
#pragma unroll
        for (int n = 0; n < 2; ++n)
#pragma unroll
            for (int e = 0; e < 4; ++e) accV[n][e] = (float)o.vtv[n * 4 + e];
#pragma unroll
        for (int kt = 0; kt < 4; ++kt) {
            accV[0] = MFMA16(o.kcf[kt], bS[kt][0], accV[0]);
            accV[1] = MFMA16(o.kcf[kt], bS[kt][1], accV[1]);
        }
#pragma unroll
        for (int n = 0; n < 2; ++n) {
            int j = n * 16 + lo, i0 = w * 16 + hi * 4;
            half4_t h4;
            h4[0] = (half_t)accV[n][0]; h4[1] = (half_t)accV[n][1];
            h4[2] = (half_t)accV[n][2]; h4[3] = (half_t)accV[n][3];
            *(half4_t*)((char*)vnT + j * 128 + ((i0 * 2) ^ ((j & 7) << 4))) = h4;
        }
        {
            float ek = expf(o.g63 - o.gi);
#pragma unroll
            for (int s = 0; s < 4; ++s)
#pragma unroll
                for (int e2 = 0; e2 < 8; ++e2)
                    w64(kdT, dseg * 32 + s * 8 + e2, ii, (float)o.k8[s][e2] * ek);
        }
        __syncthreads();
        float egm = expf(o.gm);
        f32x4 accO[2] = {};
#pragma unroll
        for (int kt = 0; kt < 4; ++kt) {
            half8 aq;
#pragma unroll
            for (int e2 = 0; e2 < 8; ++e2) aq[e2] = (half_t)((float)o.qf[kt][e2] * egm);
            accO[0] = MFMA16(aq, bS[kt][0], accO[0]);
            accO[1] = MFMA16(aq, bS[kt][1], accO[1]);
        }
#pragma unroll
        for (int kt2 = 0; kt2 < 2; ++kt2) {
            half8 bV0 = frag64(vnT, lo, kt2 * 32 + hi * 8);
            half8 bV1 = frag64(vnT, 16 + lo, kt2 * 32 + hi * 8);
            accO[0] = MFMA16(o.atf[kt2], bV0, accO[0]);
            accO[1] = MFMA16(o.atf[kt2], bV1, accO[1]);
        }
        f32x4 accU[4] = {};
#pragma unroll
        for (int kt2 = 0; kt2 < 2; ++kt2) {
            half8 avn = frag64(vnT, jm * 16 + lo, kt2 * 32 + hi * 8);
#pragma unroll
            for (int dnn = 0; dnn < 4; ++dnn) {
                half8 bkd = frag64(kdT, (dql + dnn) * 16 + lo, kt2 * 32 + hi * 8);
                accU[dnn] = MFMA16(avn, bkd, accU[dnn]);
            }
        }
#pragma unroll
        for (int n = 0; n < 2; ++n)
#pragma unroll
            for (int e = 0; e < 4; ++e)
                coreH[(rowbase + w * 16 + hi * 4 + e) * 4096 + vh * 128 + j0 + n * 16 + lo] =
                    (half_t)accO[n][e];
        __syncthreads();
        float egl = expf(o.g63);
#pragma unroll
        for (int dnn = 0; dnn < 4; ++dnn)
#pragma unroll
            for (int e = 0; e < 4; ++e) {
                int j = jm * 16 + hi * 4 + e;
                int d = (dql + dnn) * 16 + lo;
                char* p = (char*)SHs + j * 256 + ((d * 2) ^ ((j & 7) << 4));
                float old = (float)*(half_t*)p;
                *(half_t*)p = (half_t)(old * egl + accU[dnn][e]);
            }
        __syncthreads();
    };

    P2Ops opsA, opsB;
    loadops(0, opsA);
    for (int c = 0; c < 64; c += 2) {
        step(c, opsA, opsB);
        step(c + 1, opsB, opsA);
    }
}

// ---------------------------------------------------------------------------
// Gated RMSNorm + silu(z) gate, IN-PLACE on coreH. One wave per (b,s,vh) row.
// ---------------------------------------------------------------------------
__global__ __launch_bounds__(256) void normgate_k(half_t* __restrict__ coreH,
                                                  const half_t* __restrict__ zH,
                                                  const float* __restrict__ norm_w) {
    int w = threadIdx.x >> 6, lane = threadIdx.x & 63;
    long rid = (long)blockIdx.x * 4 + w;
    long bs = rid >> 5;
    int vh = rid & 31;
    half_t* cr = coreH + bs * 4096 + vh * 128;
    half2_t cv = *(half2_t*)(cr + lane * 2);
    float f0 = (float)cv[0], f1 = (float)cv[1];
    float ss = f0 * f0 + f1 * f1;
#pragma unroll
    for (int off = 32; off; off >>= 1) ss += __shfl_xor(ss, off);
    float rs = rsqrtf(ss * (1.f / 128.f) + 1e-6f);
    half2_t zz = *(const half2_t*)(zH + bs * 4096 + vh * 128 + lane * 2);
    float z0 = (float)zz[0], z1 = (float)zz[1];
    float s0 = z0 / (1.f + expf(-z0)), s1 = z1 / (1.f + expf(-z1));
    float w0 = norm_w[lane * 2], w1 = norm_w[lane * 2 + 1];
    half2_t o;
    o[0] = (half_t)(f0 * rs * w0 * s0);
    o[1] = (half_t)(f1 * rs * w1 * s1);
    *(half2_t*)(cr + lane * 2) = o;
}

// ---------------------------------------------------------------------------
// Host launcher.  Workspace layout (MiB offsets), hand-aliased:
//   [0,32)    qb      | overlay: hiddenH
//   [32,64)   kb      | overlay: W1T head (W1T = 12544x2048 f16, 51.4 MiB)
//   [64,128)  vb      | overlay: W1T tail; later coreH
//   [128,129) betaB   [129,130) gcum   [130,146) WoT
//   [146,210) zH
//   [210,349) mixedH (8192x8448 f16, 138.4 MiB) | overlay: attnW/vtW/kcW
// ---------------------------------------------------------------------------
extern "C" void kernel_launch(void* const* d_in, const int* in_sizes, int n_in,
                              void* d_out, int out_size, void* d_ws, size_t ws_size,
                              hipStream_t stream) {
    const float* hidden  = (const float*)d_in[0];
    const float* W_qkvz  = (const float*)d_in[1];
    const float* W_ba    = (const float*)d_in[2];
    const float* conv_w  = (const float*)d_in[3];
    const float* A_log   = (const float*)d_in[4];
    const float* dt_bias = (const float*)d_in[5];
    const float* norm_w  = (const float*)d_in[6];
    const float* W_out   = (const float*)d_in[7];
    float* out = (float*)d_out;

    char* ws = (char*)d_ws;
    const size_t MB = 1ull << 20;
    half_t* qb      = (half_t*)(ws + 0);
    half_t* kb      = (half_t*)(ws + 32 * MB);
    half_t* vb      = (half_t*)(ws + 64 * MB);
    float*  betaB   = (float*) (ws + 128 * MB);
    float*  gcum    = (float*) (ws + 129 * MB);
    half_t* WoT     = (half_t*)(ws + 130 * MB);
    half_t* zH      = (half_t*)(ws + 146 * MB);
    half_t* mixedH  = (half_t*)(ws + 210 * MB);
    half_t* attnW   = (half_t*)(ws + 210 * MB);
    half_t* vtW     = (half_t*)(ws + 242 * MB);
    half_t* kcW     = (half_t*)(ws + 306 * MB);
    half_t* hiddenH = (half_t*)(ws + 0);
    half_t* W1T     = (half_t*)(ws + 32 * MB);
    half_t* coreH   = (half_t*)(ws + 64 * MB);
    (void)ws_size; (void)in_sizes; (void)n_in; (void)out_size;

    // 1. casts / transposes
    cast_h_k<<<16384, 256, 0, stream>>>(hidden, hiddenH);
    build_w1t_k<<<dim3(392, 64), 256, 0, stream>>>(W_qkvz, W_ba, W1T);
    build_wot_k<<<dim3(64, 128), 256, 0, stream>>>(W_out, WoT);
    // 2. fused projection: qkv+ba (M=8192, N=8448) then z (N=4096); K=2048
    gemm256_k<1><<<32 * 33, 512, 0, stream>>>(hiddenH, W1T, mixedH, 2048, 8448, 32);
    gemm256_k<1><<<32 * 16, 512, 0, stream>>>(hiddenH, W1T + (size_t)8448 * 2048, zH,
                                              2048, 4096, 32);
    // 3. conv + silu ; gates ; l2norm
    conv_silu_k<<<dim3(32, 64), 256, 0, stream>>>(mixedH, conv_w, qb, kb, vb);
    gate_beta_k<<<128, 256, 0, stream>>>(mixedH, A_log, dt_bias, betaB, gcum);
    l2norm_k<<<65536, 256, 0, stream>>>(qb, kb);
    // 4. delta-rule core
    phase1_k<<<4096, 256, 0, stream>>>(qb, kb, vb, betaB, gcum, attnW, vtW, kcW);
    phase2_k<<<256, 256, 0, stream>>>(qb, kb, gcum, attnW, vtW, kcW, coreH);
    // 5. gated RMSNorm (in-place) + output projection (M=8192, N=2048, K=4096)
    normgate_k<<<65536, 256, 0, stream>>>(coreH, zH, norm_w);
    gemm256_k<0><<<32 * 8, 512, 0, stream>>>(coreH, WoT, out, 4096, 2048, 32);
}

// Round 6
// 1207.494 us; speedup vs baseline: 2.0432x; 1.0538x over previous
//
#include <hip/hip_runtime.h>
#include <cstdint>
#include <cstddef>

// ---------------------------------------------------------------------------
// Qwen3.5 GatedDeltaNet forward, MI355X (gfx950), f16-MFMA implementation.
// B=2, S=4096, H=2048, HK=16, HV=32, DK=DV=128, KW=4, CS=64.
// R2: phase2 split 4x across DV (grid 64 -> 256), reg-prefetch.
// R3: phase1 register-resident forward substitution.
// R4: 256x256 8-phase GEMM template (counted vmcnt(6), swizzled LDS, XCD swz).
// R5: GROUP_M=8 super-tile mapping inside the XCD swizzle — each XCD's
//     concurrent blocks cover an 8x4 tile rectangle (A-panel L2 reuse);
//     was tm-fastest (32 A panels/XCD -> 575 MB HBM over-fetch, 8.5x).
// ---------------------------------------------------------------------------

typedef _Float16 half_t;
typedef _Float16 half2_t __attribute__((ext_vector_type(2)));
typedef _Float16 half4_t __attribute__((ext_vector_type(4)));
typedef _Float16 half8   __attribute__((ext_vector_type(8)));
typedef float    f32x4   __attribute__((ext_vector_type(4)));

#define MFMA16(a, b, c) __builtin_amdgcn_mfma_f32_16x16x32_f16((a), (b), (c), 0, 0, 0)

#define AS1 __attribute__((address_space(1)))
#define AS3 __attribute__((address_space(3)))

__device__ __forceinline__ void gload16(void* lds, const void* g) {
    __builtin_amdgcn_global_load_lds((AS1 void*)(g), (AS3 void*)(lds), 16, 0, 0);
}

// ---- swizzled-LDS access helpers (XOR byte-bits 4..6 with row&7) ----------
__device__ __forceinline__ void at_wr(float* AT, int i, int j, float v) {
    *(float*)((char*)AT + i * 256 + ((j * 4) ^ ((i & 7) << 4))) = v;
}
__device__ __forceinline__ half8 frag64(const half_t* base, int row, int koff) {
    return *(const half8*)((const char*)base + row * 128 + ((koff * 2) ^ ((row & 7) << 4)));
}
__device__ __forceinline__ void w64(half_t* base, int row, int col, float v) {
    *(half_t*)((char*)base + row * 128 + ((col * 2) ^ ((row & 7) << 4))) = (half_t)v;
}
__device__ __forceinline__ half8 frag128(const half_t* base, int row, int koff) {
    return *(const half8*)((const char*)base + row * 256 + ((koff * 2) ^ ((row & 7) << 4)));
}

// ---------------------------------------------------------------------------
// Cast / transpose prep kernels
// ---------------------------------------------------------------------------
__global__ __launch_bounds__(256) void cast_h_k(const float* __restrict__ src,
                                                half_t* __restrict__ dst) {
    long i = (long)blockIdx.x * 256 + threadIdx.x;
    f32x4 v = *(const f32x4*)(src + i * 4);
    half4_t h;
    h[0] = (half_t)v[0]; h[1] = (half_t)v[1]; h[2] = (half_t)v[2]; h[3] = (half_t)v[3];
    *(half4_t*)(dst + i * 4) = h;
}

// Column-permuted W1T[n][k], n < 12544:
//   [0,2048) q | [2048,4096) k | [4096,8192) v | [8192,8256) ba |
//   [8256,8448) zero pad | [8448,12544) z
__global__ __launch_bounds__(256) void build_w1t_k(const float* __restrict__ Wq,
                                                   const float* __restrict__ Wba,
                                                   half_t* __restrict__ W1T) {
    __shared__ half_t tile[32][33];
    int n0 = blockIdx.x * 32, k0 = blockIdx.y * 32;
    int tx = threadIdx.x & 31, ty = threadIdx.x >> 5;
#pragma unroll
    for (int t = 0; t < 4; ++t) {
        int k = k0 + ty + t * 8, n = n0 + tx;
        float v = 0.f;
        if (n < 2048) {
            int kh = n >> 7, d = n & 127;
            v = Wq[(long)k * 12288 + kh * 768 + d];
        } else if (n < 4096) {
            int n2 = n - 2048; int kh = n2 >> 7, d = n2 & 127;
            v = Wq[(long)k * 12288 + kh * 768 + 128 + d];
        } else if (n < 8192) {
            int n3 = n - 4096; int vh = n3 >> 7, d = n3 & 127;
            int kh = vh >> 1, jj = vh & 1;
            v = Wq[(long)k * 12288 + kh * 768 + 256 + jj * 128 + d];
        } else if (n < 8256) {
            v = Wba[(long)k * 64 + (n - 8192)];
        } else if (n >= 8448) {
            int n4 = n - 8448; int vh = n4 >> 7, d = n4 & 127;
            int kh = vh >> 1, jj = vh & 1;
            v = Wq[(long)k * 12288 + kh * 768 + 512 + jj * 128 + d];
        }
        tile[ty + t * 8][tx] = (half_t)v;
    }
    __syncthreads();
#pragma unroll
    for (int t = 0; t < 4; ++t) {
        int n = n0 + ty + t * 8, k = k0 + tx;
        W1T[(long)n * 2048 + k] = tile[tx][ty + t * 8];
    }
}

// WoT[n][k] = W_out[k][n]; n < 2048, k < 4096
__global__ __launch_bounds__(256) void build_wot_k(const float* __restrict__ Wo,
                                                   half_t* __restrict__ WoT) {
    __shared__ half_t tile[32][33];
    int n0 = blockIdx.x * 32, k0 = blockIdx.y * 32;
    int tx = threadIdx.x & 31, ty = threadIdx.x >> 5;
#pragma unroll
    for (int t = 0; t < 4; ++t) {
        int k = k0 + ty + t * 8, n = n0 + tx;
        tile[ty + t * 8][tx] = (half_t)Wo[(long)k * 2048 + n];
    }
    __syncthreads();
#pragma unroll
    for (int t = 0; t < 4; ++t) {
        int n = n0 + ty + t * 8, k = k0 + tx;
        WoT[(long)n * 4096 + k] = tile[tx][ty + t * 8];
    }
}

// ---------------------------------------------------------------------------
// 256x256 8-phase f16 GEMM: C = A(MxK) * Bt(NxK)^T.  512 threads (8 waves,
// 2M x 4N), BK=64, LDS 128 KiB, counted vmcnt(6), raw s_barrier, setprio.
// Block mapping: bijective XCD swizzle (grid % 8 == 0) composed with a
// GROUP_M=8 super-tile walk (tm fastest within 8 rows, then tn) so each
// XCD's concurrent blocks share a compact 8-row A-panel set (L2-resident).
// ---------------------------------------------------------------------------
template <int OUT_F16>
__global__ __launch_bounds__(512, 2) void gemm256_k(const half_t* __restrict__ A,
                                                    const half_t* __restrict__ Bt,
                                                    void* __restrict__ C,
                                                    int K, int ldc,
                                                    int nwgM, int nwgN) {
    __shared__ half_t LA[2][2][8192];   // [buf][half][128 rows x 64 f16]
    __shared__ half_t LB[2][2][8192];
    const int tid = threadIdx.x, lane = tid & 63, w = tid >> 6;
    const int lo = lane & 15, hi = lane >> 4;
    const int wm = w >> 2, wn = w & 3;
    // bijective XCD swizzle (gridDim.x % 8 == 0), then GROUP_M=8 chunked map
    const int nwg = gridDim.x, q = nwg >> 3, bid = blockIdx.x;
    const int swz = (bid & 7) * q + (bid >> 3);
    const int grp = 8 * nwgN;
    const int gid = swz / grp;
    const int rem = swz - gid * grp;
    const int fm = gid * 8;
    const int gsz = min(nwgM - fm, 8);
    const long tm = fm + rem % gsz;
    const long tn = rem / gsz;
    const long Kb = (long)K * 2;
    const char* Ab = (const char*)A + tm * 256 * Kb;
    const char* Bb = (const char*)Bt + tn * 256 * Kb;
    // stage geometry: wave w writes LDS segs s0,s1 (1 KiB each, linear);
    // source column pre-swizzled so swizzled reads see logical data (rule 21).
    const int scol = ((lane & 7) << 4) ^ ((lane >> 3) << 4);
    const int srow = lane >> 3;
    const int s0 = w * 2, s1 = w * 2 + 1;

    auto stA = [&](int kt, int h) {
        char* hb = (char*)&LA[kt & 1][h][0];
        const char* gb = Ab + (long)(h * 128) * Kb + (long)kt * 128;
        gload16(hb + s0 * 1024, gb + (long)(s0 * 8 + srow) * Kb + scol);
        gload16(hb + s1 * 1024, gb + (long)(s1 * 8 + srow) * Kb + scol);
    };
    auto stB = [&](int kt, int h) {
        char* hb = (char*)&LB[kt & 1][h][0];
        const char* gb = Bb + (long)(h * 128) * Kb + (long)kt * 128;
        gload16(hb + s0 * 1024, gb + (long)(s0 * 8 + srow) * Kb + scol);
        gload16(hb + s1 * 1024, gb + (long)(s1 * 8 + srow) * Kb + scol);
    };
    auto rdA = [&](int p, int mt, int ks) -> half8 {
        int r = mt * 16 + lo;
        return *(const half8*)((const char*)&LA[p][wm][0] + r * 128 +
                               ((ks * 64 + hi * 16) ^ ((r & 7) << 4)));
    };
    auto rdB = [&](int p, int nt, int ks) -> half8 {
        int r = (wn & 1) * 64 + nt * 16 + lo;
        return *(const half8*)((const char*)&LB[p][wn >> 1][0] + r * 128 +
                               ((ks * 64 + hi * 16) ^ ((r & 7) << 4)));
    };

    f32x4 acc[8][4] = {};
    half8 af[4][2], bfa[2][2], bfb[2][2];

    auto ldsA4 = [&](int p, int mbase) {
#pragma unroll
        for (int mt = 0; mt < 4; ++mt) {
            af[mt][0] = rdA(p, mbase + mt, 0);
            af[mt][1] = rdA(p, mbase + mt, 1);
        }
    };
    auto ldsB2 = [&](int p, int nbase, half8 (&dst)[2][2]) {
#pragma unroll
        for (int nt = 0; nt < 2; ++nt) {
            dst[nt][0] = rdB(p, nbase + nt, 0);
            dst[nt][1] = rdB(p, nbase + nt, 1);
        }
    };
    auto quad = [&](const half8 (&bq)[2][2], int mo, int no) {
        __builtin_amdgcn_s_setprio(1);
#pragma unroll
        for (int mt = 0; mt < 4; ++mt)
#pragma unroll
            for (int nt = 0; nt < 2; ++nt) {
                acc[mo + mt][no + nt] = MFMA16(af[mt][0], bq[nt][0], acc[mo + mt][no + nt]);
                acc[mo + mt][no + nt] = MFMA16(af[mt][1], bq[nt][1], acc[mo + mt][no + nt]);
            }
        __builtin_amdgcn_s_setprio(0);
        __builtin_amdgcn_s_barrier();
    };

    const int nkt = K >> 6, niter = nkt >> 1;
    // prologue: K-tile 0 complete + K-tile 1 halves A0,B0,B1 (A1 at ph1)
    stA(0, 0); stA(0, 1); stB(0, 0); stB(0, 1);
    stA(1, 0); stB(1, 0); stB(1, 1);
    asm volatile("s_waitcnt vmcnt(6)" ::: "memory");
    __builtin_amdgcn_s_barrier();

    for (int i = 0; i < niter; ++i) {
        const int k0 = 2 * i, k1 = 2 * i + 1;
        const bool sa = (k0 + 2 < nkt), sb = (k1 + 2 < nkt);
        // ph1: Q(a0,b0) on k0 | stage (k1).A-hi
        ldsA4(0, 0); ldsB2(0, 0, bfa);
        stA(k1, 1);
        __builtin_amdgcn_s_barrier();
        quad(bfa, 0, 0);
        // ph2: Q(a0,b1) | B halves retire here
        ldsB2(0, 2, bfb);
        __builtin_amdgcn_s_barrier();
        quad(bfb, 0, 2);
        // ph3: Q(a1,b0) | A halves retire here | stage (k0+2).B-lo
        ldsA4(0, 4);
        if (sa) stB(k0 + 2, 0);
        __builtin_amdgcn_s_barrier();
        quad(bfa, 4, 0);
        // ph4: Q(a1,b1) | stage (k0+2).A-lo,.B-hi | counted vmcnt
        if (sa) {
            stA(k0 + 2, 0); stB(k0 + 2, 1);
            asm volatile("s_waitcnt vmcnt(6)" ::: "memory");
        } else {
            asm volatile("s_waitcnt vmcnt(0)" ::: "memory");
        }
        __builtin_amdgcn_s_barrier();
        quad(bfb, 4, 2);
        // ph5: Q(a0,b0) on k1 | stage (k0+2).A-hi
        ldsA4(1, 0); ldsB2(1, 0, bfa);
        if (sa) stA(k0 + 2, 1);
        __builtin_amdgcn_s_barrier();
        quad(bfa, 0, 0);
        // ph6: Q(a0,b1)
        ldsB2(1, 2, bfb);
        __builtin_amdgcn_s_barrier();
        quad(bfb, 0, 2);
        // ph7: Q(a1,b0) | stage (k1+2).B-lo
        ldsA4(1, 4);
        if (sb) stB(k1 + 2, 0);
        __builtin_amdgcn_s_barrier();
        quad(bfa, 4, 0);
        // ph8: Q(a1,b1) | stage (k1+2).A-lo,.B-hi | counted vmcnt
        if (sb) {
            stA(k1 + 2, 0); stB(k1 + 2, 1);
            asm volatile("s_waitcnt vmcnt(6)" ::: "memory");
        }
        __builtin_amdgcn_s_barrier();
        quad(bfb, 4, 2);
    }

    const long crow0 = tm * 256 + wm * 128 + hi * 4;
    const long ccol0 = tn * 256 + wn * 64 + lo;
#pragma unroll
    for (int mt = 0; mt < 8; ++mt)
#pragma unroll
        for (int nt = 0; nt < 4; ++nt)
#pragma unroll
            for (int e = 0; e < 4; ++e) {
                long row = crow0 + mt * 16 + e;
                long col = ccol0 + nt * 16;
                if (OUT_F16)
                    ((half_t*)C)[row * (long)ldc + col] = (half_t)acc[mt][nt][e];
                else
                    ((float*)C)[row * (long)ldc + col] = acc[mt][nt][e];
            }
}

// ---------------------------------------------------------------------------
// Causal depthwise conv (KW=4) + SiLU over mixed (B,S,8448) channels 0..8191.
// ---------------------------------------------------------------------------
__global__ __launch_bounds__(256) void conv_silu_k(const half_t* __restrict__ mixedH,
                                                   const float* __restrict__ conv_w,
                                                   half_t* __restrict__ qb,
                                                   half_t* __restrict__ kb,
                                                   half_t* __restrict__ vb) {
    int ch = blockIdx.x * 256 + threadIdx.x;
    int b = blockIdx.y >> 5, sc = blockIdx.y & 31;
    int s0 = sc * 128;
    half_t* dptr;
    long dstr;
    if (ch < 2048)      { dptr = qb + ch;          dstr = 2048; }
    else if (ch < 4096) { dptr = kb + (ch - 2048); dstr = 2048; }
    else                { dptr = vb + (ch - 4096); dstr = 4096; }
    float w0 = conv_w[ch * 4 + 0], w1 = conv_w[ch * 4 + 1];
    float w2 = conv_w[ch * 4 + 2], w3 = conv_w[ch * 4 + 3];
    const half_t* src = mixedH + (long)b * 4096 * 8448 + ch;
    float x0 = (s0 >= 3) ? (float)src[(long)(s0 - 3) * 8448] : 0.f;
    float x1 = (s0 >= 2) ? (float)src[(long)(s0 - 2) * 8448] : 0.f;
    float x2 = (s0 >= 1) ? (float)src[(long)(s0 - 1) * 8448] : 0.f;
    for (int s = s0; s < s0 + 128; ++s) {
        float x3 = (float)src[(long)s * 8448];
        float y = w0 * x0 + w1 * x1 + w2 * x2 + w3 * x3;
        y = y / (1.f + expf(-y));
        dptr[((long)b * 4096 + s) * dstr] = (half_t)y;
        x0 = x1; x1 = x2; x2 = x3;
    }
}

// ---------------------------------------------------------------------------
// beta = sigmoid(b), g = -exp(A_log)*softplus(a+dt_bias), per-chunk cumsum.
// ---------------------------------------------------------------------------
__global__ __launch_bounds__(256) void gate_beta_k(const half_t* __restrict__ mixedH,
                                                   const float* __restrict__ A_log,
                                                   const float* __restrict__ dt_bias,
                                                   float* __restrict__ beta,
                                                   float* __restrict__ gcum) {
    __shared__ float gs[32][64];
    int b = blockIdx.x >> 6, c = blockIdx.x & 63;
    for (int idx = threadIdx.x; idx < 2048; idx += 256) {
        int vh = idx & 31, i = idx >> 5;
        int kh = vh >> 1, j = vh & 1;
        long row = ((long)b * 4096 + c * 64 + i) * 8448 + 8192 + kh * 4;
        float bb = (float)mixedH[row + j];
        float aa = (float)mixedH[row + 2 + j];
        beta[((long)b * 4096 + c * 64 + i) * 32 + vh] = 1.f / (1.f + expf(-bb));
        float x = aa + dt_bias[vh];
        float sp = (x > 15.f) ? x : log1pf(expf(x));
        gs[vh][i] = -expf(A_log[vh]) * sp;
    }
    __syncthreads();
    if (threadIdx.x < 32) {
        int vh = threadIdx.x;
        float cum = 0.f;
        float* gout = gcum + ((long)(b * 32 + vh)) * 4096 + c * 64;
        for (int i = 0; i < 64; ++i) { cum += gs[vh][i]; gout[i] = cum; }
    }
}

// ---------------------------------------------------------------------------
// l2norm rows of 128 (in-place, f16). q rows get extra 1/sqrt(128).
// ---------------------------------------------------------------------------
__global__ __launch_bounds__(256) void l2norm_k(half_t* __restrict__ qb,
                                                half_t* __restrict__ kb) {
    int w = threadIdx.x >> 6, lane = threadIdx.x & 63;
    long rid = (long)blockIdx.x * 4 + w;
    half_t* base;
    float sc;
    if (rid < 131072) { base = qb + rid * 128; sc = 0.08838834764831845f; }
    else              { base = kb + (rid - 131072) * 128; sc = 1.f; }
    half2_t hv = *(half2_t*)(base + lane * 2);
    float f0 = (float)hv[0], f1 = (float)hv[1];
    float ss = f0 * f0 + f1 * f1;
#pragma unroll
    for (int off = 32; off; off >>= 1) ss += __shfl_xor(ss, off);
    float r = rsqrtf(ss + 1e-6f) * sc;
    half2_t o; o[0] = (half_t)(f0 * r); o[1] = (half_t)(f1 * r);
    *(half2_t*)(base + lane * 2) = o;
}

// ---------------------------------------------------------------------------
// Phase 1: per (b,vh,chunk): A, T=(I-A)^-1, attn, v_t, -kc.  grid 4096.
// ---------------------------------------------------------------------------
__global__ __launch_bounds__(256) void phase1_k(const half_t* __restrict__ qb,
                                                const half_t* __restrict__ kb,
                                                const half_t* __restrict__ vb,
                                                const float* __restrict__ beta,
                                                const float* __restrict__ gcum,
                                                half_t* __restrict__ attnW,
                                                half_t* __restrict__ vtW,
                                                half_t* __restrict__ kcW) {
    __shared__ float AT[64 * 64];       // swizzled rows (256 B); A f32, then T f16
    __shared__ half_t XT[256 * 64];     // rows 0..127 = (v*beta)^T, 128..255 = (k*beta*e^g)^T
    __shared__ float gcS[64], betaS[64], egS[64];
    int blk = blockIdx.x;
    int c = blk & 63, vh = (blk >> 6) & 31, b = blk >> 11;
    int kh = vh >> 1;
    int tid = threadIdx.x, lane = tid & 63, w = tid >> 6, lo = lane & 15, hi = lane >> 4;
    long rowbase = (long)b * 4096 + c * 64;
    if (tid < 64) {
        float g = gcum[((long)(b * 32 + vh)) * 4096 + c * 64 + tid];
        gcS[tid] = g; egS[tid] = expf(g);
        betaS[tid] = beta[(rowbase + tid) * 32 + vh];
    }
    const half_t* kR = kb + rowbase * 2048 + kh * 128;
    const half_t* qR = qb + rowbase * 2048 + kh * 128;
    f32x4 accG[4] = {}, accA[4] = {};
#pragma unroll
    for (int kt = 0; kt < 4; ++kt) {
        half8 ak = *(const half8*)(kR + (long)(w * 16 + lo) * 2048 + kt * 32 + hi * 8);
        half8 aq = *(const half8*)(qR + (long)(w * 16 + lo) * 2048 + kt * 32 + hi * 8);
#pragma unroll
        for (int n = 0; n < 4; ++n) {
            half8 bk = *(const half8*)(kR + (long)(n * 16 + lo) * 2048 + kt * 32 + hi * 8);
            accG[n] = MFMA16(ak, bk, accG[n]);
            accA[n] = MFMA16(aq, bk, accA[n]);
        }
    }
    __syncthreads();
    half_t* attnB = attnW + (long)blk * 4096;
#pragma unroll
    for (int n = 0; n < 4; ++n)
#pragma unroll
        for (int e = 0; e < 4; ++e) {
            int i = w * 16 + hi * 4 + e;
            int j = n * 16 + lo;
            float dec = (j < i) ? expf(gcS[i] - gcS[j]) : 0.f;
            float av = (j < i) ? (-betaS[i] * accG[n][e] * dec) : (j == i ? 1.f : 0.f);
            at_wr(AT, i, j, av);
            attnB[(long)i * 64 + j] = (half_t)((j < i) ? accA[n][e] * dec : 0.f);
        }
    __syncthreads();
    if (w == 0) {
        float t[64];
#pragma unroll
        for (int i = 0; i < 64; ++i) t[i] = (lane == i) ? 1.f : 0.f;
#pragma unroll
        for (int i = 1; i < 64; ++i) {
            float a0 = 0.f, a1 = 0.f, a2 = 0.f, a3 = 0.f;
#pragma unroll
            for (int p0 = 0; p0 < i; p0 += 4) {
                f32x4 a4 = *(const f32x4*)((const char*)AT + i * 256 +
                                           ((p0 * 4) ^ ((i & 7) << 4)));
                if (p0 + 0 < i) a0 += a4[0] * t[p0 + 0];
                if (p0 + 1 < i) a1 += a4[1] * t[p0 + 1];
                if (p0 + 2 < i) a2 += a4[2] * t[p0 + 2];
                if (p0 + 3 < i) a3 += a4[3] * t[p0 + 3];
            }
            t[i] += (a0 + a1) + (a2 + a3);
        }
        half_t* TS = (half_t*)AT;
#pragma unroll
        for (int i = 0; i < 64; ++i)
            *(half_t*)((char*)TS + i * 128 + ((lane * 2) ^ ((i & 7) << 4))) = (half_t)t[i];
    } else {
        for (int idx = tid - 64; idx < 4096; idx += 192) {
            int p = idx >> 6, dp = idx & 63;
            float bb = betaS[p], be = betaS[p] * egS[p];
            half2_t vv = *(const half2_t*)(vb + (rowbase + p) * 4096 + vh * 128 + dp * 2);
            half2_t kk = *(const half2_t*)(kb + (rowbase + p) * 2048 + kh * 128 + dp * 2);
            w64(XT, dp * 2,       p, (float)vv[0] * bb);
            w64(XT, dp * 2 + 1,   p, (float)vv[1] * bb);
            w64(XT, 128 + dp * 2,     p, (float)kk[0] * be);
            w64(XT, 128 + dp * 2 + 1, p, (float)kk[1] * be);
        }
    }
    __syncthreads();
    const half_t* TS = (const half_t*)AT;
    f32x4 accO[4][4] = {};
#pragma unroll
    for (int kt = 0; kt < 2; ++kt) {
        half8 tf[4];
#pragma unroll
        for (int m = 0; m < 4; ++m) tf[m] = frag64(TS, m * 16 + lo, kt * 32 + hi * 8);
#pragma unroll
        for (int n = 0; n < 4; ++n) {
            half8 bx = frag64(XT, w * 64 + n * 16 + lo, kt * 32 + hi * 8);
#pragma unroll
            for (int m = 0; m < 4; ++m) accO[m][n] = MFMA16(tf[m], bx, accO[m][n]);
        }
    }
    long ob = (long)blk * 8192;
#pragma unroll
    for (int m = 0; m < 4; ++m)
#pragma unroll
        for (int n = 0; n < 4; ++n)
#pragma unroll
            for (int e = 0; e < 4; ++e) {
                int i = m * 16 + hi * 4 + e;
                int dc = w * 64 + n * 16 + lo;
                float v = accO[m][n][e];
                if (dc < 128) vtW[ob + (long)i * 128 + dc] = (half_t)v;
                else          kcW[ob + (long)i * 128 + dc - 128] = (half_t)(-v);
            }
}

// ---------------------------------------------------------------------------
// Phase 2: sequential chunk scan per (b,vh,DV-slice of 32). grid 256.
// ---------------------------------------------------------------------------
struct P2Ops {
    half8 kcf[4], qf[4], k8[4];
    half8 atf[2];
    half_t vtv[8];
    float gm, gi, g63;
};

__global__ __launch_bounds__(256, 1) void phase2_k(const half_t* __restrict__ qb,
                                                   const half_t* __restrict__ kb,
                                                   const float* __restrict__ gcum,
                                                   const half_t* __restrict__ attnW,
                                                   const half_t* __restrict__ vtW,
                                                   const half_t* __restrict__ kcW,
                                                   half_t* __restrict__ coreH) {
    __shared__ half_t SHs[32 * 128];
    __shared__ half_t vnT[32 * 64];
    __shared__ half_t kdT[128 * 64];
    int blk = blockIdx.x;
    int bvh = blk & 63, js = blk >> 6;
    int vh = bvh & 31, b = bvh >> 5, kh = vh >> 1;
    int j0 = js * 32;
    int tid = threadIdx.x, lane = tid & 63, w = tid >> 6, lo = lane & 15, hi = lane >> 4;
    int ii = tid >> 2, dseg = tid & 3;
    int jm = w >> 1, dql = (w & 1) * 4;
    for (int idx = tid; idx < 32 * 128; idx += 256) SHs[idx] = (half_t)0.f;
    __syncthreads();
    const float* gbase = gcum + (long)bvh * 4096;

    auto loadops = [&](int c, P2Ops& o) {
        long pb = (long)bvh * 64 + c;
        const half_t* kcG = kcW + pb * 8192;
        const half_t* vtG = vtW + pb * 8192;
        const half_t* atG = attnW + pb * 4096;
        long rowbase = (long)b * 4096 + c * 64;
        const float* gp = gbase + c * 64;
#pragma unroll
        for (int kt = 0; kt < 4; ++kt) {
            o.kcf[kt] = *(const half8*)(kcG + (long)(w * 16 + lo) * 128 + kt * 32 + hi * 8);
            o.qf[kt] = *(const half8*)(qb + (rowbase + w * 16 + lo) * 2048 + kh * 128 +
                                       kt * 32 + hi * 8);
        }
#pragma unroll
        for (int kt2 = 0; kt2 < 2; ++kt2)
            o.atf[kt2] = *(const half8*)(atG + (long)(w * 16 + lo) * 64 + kt2 * 32 + hi * 8);
#pragma unroll
        for (int s = 0; s < 4; ++s)
            o.k8[s] = *(const half8*)(kb + (rowbase + ii) * 2048 + kh * 128 + dseg * 32 + s * 8);
#pragma unroll
        for (int n = 0; n < 2; ++n)
#pragma unroll
            for (int e = 0; e < 4; ++e)
                o.vtv[n * 4 + e] = vtG[(long)(w * 16 + hi * 4 + e) * 128 + j0 + n * 16 + lo];
        o.gm = gp[w * 16 + lo];
        o.gi = gp[ii];
        o.g63 = gp[63];
    };

    auto step = [&](int c, P2Ops& o, P2Ops& nx) {
        long rowbase = (long)b * 4096 + c * 64;
        loadops(c + 1 < 64 ? c + 1 : 63, nx);
        half8 bS[4][2];
#pragma unroll
        for (int kt = 0; kt < 4; ++kt) {
            bS[kt][0] = frag128(SHs, lo, kt * 32 + hi * 8);
            bS[kt][1] = frag128(SHs, 16 + lo, kt * 32 + hi * 8);
        }
        f32x4 accV[2];
#pragma unroll
        for (int n = 0; n < 2; ++n)
#pragma unroll
            for (int e = 0; e < 4; ++e) accV[n][e] = (float)o.vtv[n * 4 + e];
#pragma unroll
        for (int kt = 0; kt < 4; ++kt) {
            accV[0] = MFMA16(o.kcf[kt], bS[kt][0], accV[0]);
            accV[1] = MFMA16(o.kcf[kt], bS[kt][1], accV[1]);
        }
#pragma unroll
        for (int n = 0; n < 2; ++n) {
            int j = n * 16 + lo, i0 = w * 16 + hi * 4;
            half4_t h4;
            h4[0] = (half_t)accV[n][0]; h4[1] = (half_t)accV[n][1];
            h4[2] = (half_t)accV[n][2]; h4[3] = (half_t)accV[n][3];
            *(half4_t*)((char*)vnT + j * 128 + ((i0 * 2) ^ ((j & 7) << 4))) = h4;
        }
        {
            float ek = expf(o.g63 - o.gi);
#pragma unroll
            for (int s = 0; s < 4; ++s)
#pragma unroll
                for (int e2 = 0; e2 < 8; ++e2)
                    w64(kdT, dseg * 32 + s * 8 + e2, ii, (float)o.k8[s][e2] * ek);
        }
        __syncthreads();
        float egm = expf(o.gm);
        f32x4 accO[2] = {};
#pragma unroll
        for (int kt = 0; kt < 4; ++kt) {
            half8 aq;
#pragma unroll
            for (int e2 = 0; e2 < 8; ++e2) aq[e2] = (half_t)((float)o.qf[kt][e2] * egm);
            accO[0] = MFMA16(aq, bS[kt][0], accO[0]);
            accO[1] = MFMA16(aq, bS[kt][1], accO[1]);
        }
#pragma unroll
        for (int kt2 = 0; kt2 < 2; ++kt2) {
            half8 bV0 = frag64(vnT, lo, kt2 * 32 + hi * 8);
            half8 bV1 = frag64(vnT, 16 + lo, kt2 * 32 + hi * 8);
            accO[0] = MFMA16(o.atf[kt2], bV0, accO[0]);
            accO[1] = MFMA16(o.atf[kt2], bV1, accO[1]);
        }
        f32x4 accU[4] = {};
#pragma unroll
        for (int kt2 = 0; kt2 < 2; ++kt2) {
            half8 avn = frag64(vnT, jm * 16 + lo, kt2 * 32 + hi * 8);
#pragma unroll
            for (int dnn = 0; dnn < 4; ++dnn) {
                half8 bkd = frag64(kdT, (dql + dnn) * 16 + lo, kt2 * 32 + hi * 8);
                accU[dnn] = MFMA16(avn, bkd, accU[dnn]);
            }
        }
#pragma unroll
        for (int n = 0; n < 2; ++n)
#pragma unroll
            for (int e = 0; e < 4; ++e)
                coreH[(rowbase + w * 16 + hi * 4 + e) * 4096 + vh * 128 + j0 + n * 16 + lo] =
                    (half_t)accO[n][e];
        __syncthreads();
        float egl = expf(o.g63);
#pragma unroll
        for (int dnn = 0; dnn < 4; ++dnn)
#pragma unroll
            for (int e = 0; e < 4; ++e) {
                int j = jm * 16 + hi * 4 + e;
                int d = (dql + dnn) * 16 + lo;
                char* p = (char*)SHs + j * 256 + ((d * 2) ^ ((j & 7) << 4));
                float old = (float)*(half_t*)p;
                *(half_t*)p = (half_t)(old * egl + accU[dnn][e]);
            }
        __syncthreads();
    };

    P2Ops opsA, opsB;
    loadops(0, opsA);
    for (int c = 0; c < 64; c += 2) {
        step(c, opsA, opsB);
        step(c + 1, opsB, opsA);
    }
}

// ---------------------------------------------------------------------------
// Gated RMSNorm + silu(z) gate, IN-PLACE on coreH. One wave per (b,s,vh) row.
// ---------------------------------------------------------------------------
__global__ __launch_bounds__(256) void normgate_k(half_t* __restrict__ coreH,
                                                  const half_t* __restrict__ zH,
                                                  const float* __restrict__ norm_w) {
    int w = threadIdx.x >> 6, lane = threadIdx.x & 63;
    long rid = (long)blockIdx.x * 4 + w;
    long bs = rid >> 5;
    int vh = rid & 31;
    half_t* cr = coreH + bs * 4096 + vh * 128;
    half2_t cv = *(half2_t*)(cr + lane * 2);
    float f0 = (float)cv[0], f1 = (float)cv[1];
    float ss = f0 * f0 + f1 * f1;
#pragma unroll
    for (int off = 32; off; off >>= 1) ss += __shfl_xor(ss, off);
    float rs = rsqrtf(ss * (1.f / 128.f) + 1e-6f);
    half2_t zz = *(const half2_t*)(zH + bs * 4096 + vh * 128 + lane * 2);
    float z0 = (float)zz[0], z1 = (float)zz[1];
    float s0 = z0 / (1.f + expf(-z0)), s1 = z1 / (1.f + expf(-z1));
    float w0 = norm_w[lane * 2], w1 = norm_w[lane * 2 + 1];
    half2_t o;
    o[0] = (half_t)(f0 * rs * w0 * s0);
    o[1] = (half_t)(f1 * rs * w1 * s1);
    *(half2_t*)(cr + lane * 2) = o;
}

// ---------------------------------------------------------------------------
// Host launcher.  Workspace layout (MiB offsets), hand-aliased:
//   [0,32)    qb      | overlay: hiddenH
//   [32,64)   kb      | overlay: W1T head (W1T = 12544x2048 f16, 51.4 MiB)
//   [64,128)  vb      | overlay: W1T tail; later coreH
//   [128,129) betaB   [129,130) gcum   [130,146) WoT
//   [146,210) zH
//   [210,349) mixedH (8192x8448 f16, 138.4 MiB) | overlay: attnW/vtW/kcW
// ---------------------------------------------------------------------------
extern "C" void kernel_launch(void* const* d_in, const int* in_sizes, int n_in,
                              void* d_out, int out_size, void* d_ws, size_t ws_size,
                              hipStream_t stream) {
    const float* hidden  = (const float*)d_in[0];
    const float* W_qkvz  = (const float*)d_in[1];
    const float* W_ba    = (const float*)d_in[2];
    const float* conv_w  = (const float*)d_in[3];
    const float* A_log   = (const float*)d_in[4];
    const float* dt_bias = (const float*)d_in[5];
    const float* norm_w  = (const float*)d_in[6];
    const float* W_out   = (const float*)d_in[7];
    float* out = (float*)d_out;

    char* ws = (char*)d_ws;
    const size_t MB = 1ull << 20;
    half_t* qb      = (half_t*)(ws + 0);
    half_t* kb      = (half_t*)(ws + 32 * MB);
    half_t* vb      = (half_t*)(ws + 64 * MB);
    float*  betaB   = (float*) (ws + 128 * MB);
    float*  gcum    = (float*) (ws + 129 * MB);
    half_t* WoT     = (half_t*)(ws + 130 * MB);
    half_t* zH      = (half_t*)(ws + 146 * MB);
    half_t* mixedH  = (half_t*)(ws + 210 * MB);
    half_t* attnW   = (half_t*)(ws + 210 * MB);
    half_t* vtW     = (half_t*)(ws + 242 * MB);
    half_t* kcW     = (half_t*)(ws + 306 * MB);
    half_t* hiddenH = (half_t*)(ws + 0);
    half_t* W1T     = (half_t*)(ws + 32 * MB);
    half_t* coreH   = (half_t*)(ws + 64 * MB);
    (void)ws_size; (void)in_sizes; (void)n_in; (void)out_size;

    // 1. casts / transposes
    cast_h_k<<<16384, 256, 0, stream>>>(hidden, hiddenH);
    build_w1t_k<<<dim3(392, 64), 256, 0, stream>>>(W_qkvz, W_ba, W1T);
    build_wot_k<<<dim3(64, 128), 256, 0, stream>>>(W_out, WoT);
    // 2. fused projection: qkv+ba (M=8192, N=8448) then z (N=4096); K=2048
    gemm256_k<1><<<32 * 33, 512, 0, stream>>>(hiddenH, W1T, mixedH, 2048, 8448, 32, 33);
    gemm256_k<1><<<32 * 16, 512, 0, stream>>>(hiddenH, W1T + (size_t)8448 * 2048, zH,
                                              2048, 4096, 32, 16);
    // 3. conv + silu ; gates ; l2norm
    conv_silu_k<<<dim3(32, 64), 256, 0, stream>>>(mixedH, conv_w, qb, kb, vb);
    gate_beta_k<<<128, 256, 0, stream>>>(mixedH, A_log, dt_bias, betaB, gcum);
    l2norm_k<<<65536, 256, 0, stream>>>(qb, kb);
    // 4. delta-rule core
    phase1_k<<<4096, 256, 0, stream>>>(qb, kb, vb, betaB, gcum, attnW, vtW, kcW);
    phase2_k<<<256, 256, 0, stream>>>(qb, kb, gcum, attnW, vtW, kcW, coreH);
    // 5. gated RMSNorm (in-place) + output projection (M=8192, N=2048, K=4096)
    normgate_k<<<65536, 256, 0, stream>>>(coreH, zH, norm_w);
    gemm256_k<0><<<32 * 8, 512, 0, stream>>>(coreH, WoT, out, 4096, 2048, 32, 8);
}